// Round 1
// baseline (605.164 us; speedup 1.0000x reference)
//
#include <hip/hip_runtime.h>
#include <cstdint>
#include <cmath>

// Problem constants (T=1024, HID=7168, R=1536, H=64, D=128, RD=64, TOPK=512)
#define NT 1024
#define NHID 7168
#define NR 1536
#define NH 64
#define ND 128
#define NTOPK 512

typedef float f32x4 __attribute__((ext_vector_type(4)));

// ---------------------------------------------------------------- rope table
__global__ void rope_table_k(const int* __restrict__ pos,
                             float* __restrict__ cost, float* __restrict__ sint) {
  int i = threadIdx.x;
  int t = blockIdx.x;
  if (i < 32) {
    double x = (double)(2 * i) / 64.0;       // exact
    double p = pow(10000.0, x);              // correctly-rounded-ish
    float p32 = (float)p;                    // THETA ** x in f32
    float invf = __fdiv_rn(1.0f, p32);       // 1.0 / (f32) in f32
    float ang = __fmul_rn((float)pos[t], invf);
    cost[t * 32 + i] = (float)cos((double)ang);
    sint[t * 32 + i] = (float)sin((double)ang);
  }
}

// ---------------------------------------------------------------- f32 GEMM
// BM=128, BN=64, BK=16, 256 threads, 8x4 per-thread tile, optional split-K.
// C layout: C[kidx*M*N + m*N + n]
__global__ __launch_bounds__(256)
void gemm_f32_k(const float* __restrict__ A, const float* __restrict__ B,
                float* __restrict__ C, int M, int N, int K,
                int lda, int ldb, int kchunk) {
  __shared__ float At[16][128];
  __shared__ float Bs[16][64];
  int tid = threadIdx.x;
  int n0 = blockIdx.x * 64;
  int m0 = blockIdx.y * 128;
  int k0 = blockIdx.z * kchunk;
  int ty = tid >> 4, tx = tid & 15;

  float acc[8][4];
#pragma unroll
  for (int i = 0; i < 8; i++)
#pragma unroll
    for (int j = 0; j < 4; j++) acc[i][j] = 0.0f;

  for (int kb = 0; kb < kchunk; kb += 16) {
    int kk0 = k0 + kb;
    {  // A tile 128x16, transposed store
      int r = tid >> 2;
      int c4 = (tid & 3) * 4;
      const float* pa = A + (size_t)(m0 + r) * lda + kk0 + c4;
      f32x4 v0 = *(const f32x4*)pa;
      f32x4 v1 = *(const f32x4*)(pa + (size_t)64 * lda);
#pragma unroll
      for (int i = 0; i < 4; i++) {
        At[c4 + i][r] = v0[i];
        At[c4 + i][r + 64] = v1[i];
      }
    }
    {  // B tile 16x64
      int r = tid >> 4;
      int c4 = (tid & 15) * 4;
      f32x4 v = *(const f32x4*)(B + (size_t)(kk0 + r) * ldb + n0 + c4);
      *(f32x4*)&Bs[r][c4] = v;
    }
    __syncthreads();
#pragma unroll
    for (int kk = 0; kk < 16; kk++) {
      f32x4 a0 = *(const f32x4*)&At[kk][ty * 8];
      f32x4 a1 = *(const f32x4*)&At[kk][ty * 8 + 4];
      f32x4 b = *(const f32x4*)&Bs[kk][tx * 4];
#pragma unroll
      for (int i = 0; i < 4; i++)
#pragma unroll
        for (int j = 0; j < 4; j++) {
          acc[i][j] = fmaf(a0[i], b[j], acc[i][j]);
          acc[4 + i][j] = fmaf(a1[i], b[j], acc[4 + i][j]);
        }
    }
    __syncthreads();
  }
  size_t base = (size_t)blockIdx.z * M * N;
#pragma unroll
  for (int i = 0; i < 8; i++) {
    int m = m0 + ty * 8 + i;
    float* pc = C + base + (size_t)m * N + n0 + tx * 4;
    f32x4 v = {acc[i][0], acc[i][1], acc[i][2], acc[i][3]};
    *(f32x4*)pc = v;
  }
}

// ---------------------------------------------------------- rope+fwht+quant
// One wave per 128-elem row: lane l owns elements l and l+64.
__device__ __forceinline__ void rope_fwht_quant(
    float v0, float v1, int l, int pos_t,
    const float* __restrict__ cost, const float* __restrict__ sint,
    uint8_t* __restrict__ out_bytes, float* __restrict__ out_scale) {
  // --- rope on elements 0..63 (interleaved_to_half + rope_half fused)
  float a = __shfl(v0, (2 * l) & 63, 64);      // x[2i]
  float b = __shfl(v0, (2 * l + 1) & 63, 64);  // x[2i+1]
  int fi = l & 31;
  float c = cost[pos_t * 32 + fi];
  float sn = sint[pos_t * 32 + fi];
  float r;
  if (l < 32)
    r = __fsub_rn(__fmul_rn(a, c), __fmul_rn(b, sn));  // x1*cos - x2*sin
  else
    r = __fadd_rn(__fmul_rn(b, c), __fmul_rn(a, sn));  // x2*cos + x1*sin
  v0 = r;  // v1 (elements 64..127) untouched by rope

  // --- FWHT (Sylvester order: m = 1,2,...,64)
#pragma unroll
  for (int m = 1; m < 64; m <<= 1) {
    float p0 = __shfl_xor(v0, m, 64);
    float p1 = __shfl_xor(v1, m, 64);
    bool up = (l & m) == 0;
    v0 = up ? __fadd_rn(v0, p0) : __fsub_rn(p0, v0);
    v1 = up ? __fadd_rn(v1, p1) : __fsub_rn(p1, v1);
  }
  {  // m = 64: pair (l, l+64) is lane-local
    float A0 = v0, B0 = v1;
    v0 = __fadd_rn(A0, B0);
    v1 = __fsub_rn(A0, B0);
  }
  const float WS = 0.08838834764831843f;  // 128^-0.5 in f32
  v0 = __fmul_rn(v0, WS);
  v1 = __fmul_rn(v1, WS);

  // --- fp8 e4m3 quant with UE8M0 scale
  float am = fmaxf(fabsf(v0), fabsf(v1));
#pragma unroll
  for (int m = 1; m < 64; m <<= 1) am = fmaxf(am, __shfl_xor(am, m, 64));
  am = fmaxf(am, 1e-4f);
  float ratio = __fdiv_rn(am, 448.0f);
  float l2 = (float)log2((double)ratio);
  float e = ceilf(l2);
  float sf = exp2f(e);                 // exact power of two
  float inv = __fdiv_rn(1.0f, sf);     // exact
  float q0 = __fmul_rn(v0, inv);       // exact (pow2 scale)
  float q1 = __fmul_rn(v1, inv);
  int b0 = __builtin_amdgcn_cvt_pk_fp8_f32(q0, q0, 0, false);  // RNE, OCP e4m3
  int b1 = __builtin_amdgcn_cvt_pk_fp8_f32(q1, q1, 0, false);
  out_bytes[l] = (uint8_t)(b0 & 0xff);
  out_bytes[l + 64] = (uint8_t)(b1 & 0xff);
  if (l == 0) *out_scale = sf;
}

// --------------------------------------------------------------- k finalize
__global__ __launch_bounds__(256)
void k_finalize_k(const float* __restrict__ kpart, const float* __restrict__ gamma,
                  const float* __restrict__ beta, const float* __restrict__ cost,
                  const float* __restrict__ sint, uint8_t* __restrict__ kfp8,
                  float* __restrict__ kscale) {
  int l = threadIdx.x & 63;
  int row = blockIdx.x * 4 + (threadIdx.x >> 6);  // t
  // deterministic split-K reduce (8 parts)
  float v0 = 0.0f, v1 = 0.0f;
#pragma unroll
  for (int p = 0; p < 8; p++) {
    v0 = __fadd_rn(v0, kpart[(size_t)p * (NT * ND) + row * ND + l]);
    v1 = __fadd_rn(v1, kpart[(size_t)p * (NT * ND) + row * ND + l + 64]);
  }
  // layernorm over 128
  float s = __fadd_rn(v0, v1);
#pragma unroll
  for (int m = 1; m < 64; m <<= 1) s = __fadd_rn(s, __shfl_xor(s, m, 64));
  float mu = __fmul_rn(s, 0.0078125f);
  float d0 = __fsub_rn(v0, mu), d1 = __fsub_rn(v1, mu);
  float vs = __fadd_rn(__fmul_rn(d0, d0), __fmul_rn(d1, d1));
#pragma unroll
  for (int m = 1; m < 64; m <<= 1) vs = __fadd_rn(vs, __shfl_xor(vs, m, 64));
  float var = __fmul_rn(vs, 0.0078125f);
  float rs = (float)(1.0 / sqrt((double)__fadd_rn(var, 1e-5f)));
  v0 = __fadd_rn(__fmul_rn(__fmul_rn(d0, rs), gamma[l]), beta[l]);
  v1 = __fadd_rn(__fmul_rn(__fmul_rn(d1, rs), gamma[l + 64]), beta[l + 64]);
  rope_fwht_quant(v0, v1, l, row, cost, sint, kfp8 + (size_t)row * ND, kscale + row);
}

// --------------------------------------------------------------- q finalize
__global__ __launch_bounds__(256)
void q_finalize_k(const float* __restrict__ qraw, const float* __restrict__ cost,
                  const float* __restrict__ sint, uint8_t* __restrict__ qfp8,
                  float* __restrict__ qscale) {
  int l = threadIdx.x & 63;
  int row = blockIdx.x * 4 + (threadIdx.x >> 6);  // t*64 + h
  int t = row >> 6;
  float v0 = qraw[(size_t)row * ND + l];
  float v1 = qraw[(size_t)row * ND + l + 64];
  rope_fwht_quant(v0, v1, l, t, cost, sint, qfp8 + (size_t)row * ND, qscale + row);
}

// ------------------------------------------------------------------ weights
__global__ __launch_bounds__(256)
void weights_k(const float* __restrict__ wpart, const float* __restrict__ qscale,
               float* __restrict__ weights) {
  int i = blockIdx.x * 256 + threadIdx.x;  // t*64 + h
  float s = 0.0f;
#pragma unroll
  for (int p = 0; p < 16; p++) s = __fadd_rn(s, wpart[(size_t)p * (NT * NH) + i]);
  float w = __fmul_rn(s, 0.125f);                   // * H^-0.5
  w = __fmul_rn(w, qscale[i]);                      // * q_scale
  w = __fmul_rn(w, 0.08838834764831843f);           // * SM_SCALE
  weights[i] = w;
}

// ------------------------------------------------------------------- scores
// grid = 1024 (t), 256 threads = 4 waves; wave w owns heads 16w..16w+15.
// spart[(t*4+w)*1024 + s] = sum over the wave's 16 heads of w_h*relu(logit).
__global__ __launch_bounds__(256)
void scores_k(const uint8_t* __restrict__ qfp8, const uint8_t* __restrict__ kfp8,
              const float* __restrict__ kscale, const float* __restrict__ weights,
              float* __restrict__ spart) {
  int t = blockIdx.x;
  int tid = threadIdx.x;
  int w = tid >> 6, lane = tid & 63;
  int lg = lane >> 4;   // k-group / acc row-group
  int ln = lane & 15;   // A row / B col within 16

  float wj[4];
#pragma unroll
  for (int j = 0; j < 4; j++) wj[j] = weights[t * NH + w * 16 + lg * 4 + j];

  long afr[4];
  const uint8_t* qrow = qfp8 + (size_t)(t * NH + w * 16 + ln) * ND;
#pragma unroll
  for (int ks = 0; ks < 4; ks++) afr[ks] = *(const long*)(qrow + ks * 32 + lg * 8);

  for (int s0 = 0; s0 <= t; s0 += 64) {
    float psum[4];
#pragma unroll
    for (int sub = 0; sub < 4; sub++) {
      int s = s0 + sub * 16 + ln;
      const uint8_t* krow = kfp8 + (size_t)s * ND;
      f32x4 acc = {0.0f, 0.0f, 0.0f, 0.0f};
#pragma unroll
      for (int ks = 0; ks < 4; ks++) {
        long bfr = *(const long*)(krow + ks * 32 + lg * 8);
        acc = __builtin_amdgcn_mfma_f32_16x16x32_fp8_fp8(afr[ks], bfr, acc, 0, 0, 0);
      }
      float ksc = kscale[s];
      float p = 0.0f;
#pragma unroll
      for (int j = 0; j < 4; j++) {
        float logit = __fmul_rn(acc[j], ksc);  // exact pow2 factoring
        p = fmaf(wj[j], fmaxf(logit, 0.0f), p);
      }
      psum[sub] = p;
    }
#pragma unroll
    for (int sub = 0; sub < 4; sub++) {
      float p = psum[sub];
      p += __shfl_xor(p, 16, 64);
      p += __shfl_xor(p, 32, 64);
      if (lg == 0)
        spart[((size_t)t * 4 + w) * NT + s0 + sub * 16 + ln] = p;
    }
  }
}

// -------------------------------------------------------------------- top-k
// Bitonic sort of 1024 (value desc, index asc) keys; exact lax.top_k order.
__global__ __launch_bounds__(256)
void topk_k(const float* __restrict__ spart, float* __restrict__ outv,
            float* __restrict__ outi) {
  __shared__ unsigned long long key[1024];
  int t = blockIdx.x, tid = threadIdx.x;
#pragma unroll
  for (int p = 0; p < 4; p++) {
    int s = tid + p * 256;
    float v;
    if (s <= t) {
      float a = spart[((size_t)t * 4 + 0) * NT + s];
      a = __fadd_rn(a, spart[((size_t)t * 4 + 1) * NT + s]);
      a = __fadd_rn(a, spart[((size_t)t * 4 + 2) * NT + s]);
      a = __fadd_rn(a, spart[((size_t)t * 4 + 3) * NT + s]);
      v = a;
    } else {
      v = -1e30f;
    }
    unsigned u = __float_as_uint(v);
    unsigned ou = (u & 0x80000000u) ? ~u : (u | 0x80000000u);
    key[s] = ((unsigned long long)ou << 32) | (unsigned)(~(unsigned)s);
  }
  for (int k = 2; k <= 1024; k <<= 1) {
    for (int j = k >> 1; j > 0; j >>= 1) {
      __syncthreads();
#pragma unroll
      for (int p = 0; p < 2; p++) {
        int i = tid + p * 256;
        int l = ((i & ~(j - 1)) << 1) | (i & (j - 1));
        int m = l + j;
        bool desc = ((l & k) == 0);
        unsigned long long a = key[l], b = key[m];
        if (desc ? (a < b) : (a > b)) {
          key[l] = b;
          key[m] = a;
        }
      }
    }
  }
  __syncthreads();
#pragma unroll
  for (int p = 0; p < 2; p++) {
    int r = tid + p * 256;
    unsigned long long kk = key[r];
    unsigned ou = (unsigned)(kk >> 32);
    unsigned u = (ou & 0x80000000u) ? (ou ^ 0x80000000u) : ~ou;
    unsigned idx = (~(unsigned)(kk & 0xffffffffu)) & 1023u;
    outv[(size_t)t * NTOPK + r] = __uint_as_float(u);
    outi[(size_t)t * NTOPK + r] = (float)idx;  // idx chunk read as f32 by harness
  }
}

// ------------------------------------------------------------------- launch
extern "C" void kernel_launch(void* const* d_in, const int* in_sizes, int n_in,
                              void* d_out, int out_size, void* d_ws, size_t ws_size,
                              hipStream_t stream) {
  const float* hidden = (const float*)d_in[0];
  const float* q_lora = (const float*)d_in[1];
  const int* positions = (const int*)d_in[2];
  const float* wq_b = (const float*)d_in[3];
  const float* wk = (const float*)d_in[4];
  const float* w_proj = (const float*)d_in[5];
  const float* ln_g = (const float*)d_in[6];
  const float* ln_b = (const float*)d_in[7];
  float* out = (float*)d_out;

  float* ws = (float*)d_ws;
  float* kpart = ws;                              //  8 * 1024*128
  float* wpart = kpart + 8 * NT * ND;             // 16 * 1024*64
  float* qraw = wpart + 16 * NT * NH;             // 1024*8192
  float* cost = qraw + (size_t)NT * NH * ND;      // 1024*32
  float* sint = cost + NT * 32;                   // 1024*32
  float* kscale = sint + NT * 32;                 // 1024
  float* qscale = kscale + NT;                    // 65536
  float* weights = qscale + NT * NH;              // 65536
  float* spart = weights + NT * NH;               // 1024*4*1024
  uint8_t* kfp8 = (uint8_t*)(spart + (size_t)NT * 4 * NT);  // 131072 B
  uint8_t* qfp8 = kfp8 + (size_t)NT * ND;                   // 8388608 B

  rope_table_k<<<NT, 64, 0, stream>>>(positions, cost, sint);
  // k projection: hidden @ wk  (M=1024,N=128,K=7168, split-K=8, chunk 896)
  gemm_f32_k<<<dim3(2, 8, 8), 256, 0, stream>>>(hidden, wk, kpart,
                                                NT, ND, NHID, NHID, ND, 896);
  // weights raw: hidden @ w_proj (N=64, split-K=16, chunk 448)
  gemm_f32_k<<<dim3(1, 8, 16), 256, 0, stream>>>(hidden, w_proj, wpart,
                                                 NT, NH, NHID, NHID, NH, 448);
  // q: q_lora @ wq_b (M=1024,N=8192,K=1536, no split)
  gemm_f32_k<<<dim3(128, 8, 1), 256, 0, stream>>>(q_lora, wq_b, qraw,
                                                  NT, NH * ND, NR, NR, NH * ND, NR);
  k_finalize_k<<<NT / 4, 256, 0, stream>>>(kpart, ln_g, ln_b, cost, sint, kfp8, kscale);
  q_finalize_k<<<NT * NH / 4, 256, 0, stream>>>(qraw, cost, sint, qfp8, qscale);
  weights_k<<<NT * NH / 256, 256, 0, stream>>>(wpart, qscale, weights);
  scores_k<<<NT, 256, 0, stream>>>(qfp8, kfp8, kscale, weights, spart);
  topk_k<<<NT, 256, 0, stream>>>(spart, out, out + (size_t)NT * NTOPK);
}

// Round 2
// 229.082 us; speedup vs baseline: 2.6417x; 2.6417x over previous
//
#include <hip/hip_runtime.h>
#include <cstdint>
#include <cmath>

// Problem constants (T=1024, HID=7168, R=1536, H=64, D=128, RD=64, TOPK=512)
#define NT 1024
#define NHID 7168
#define NR 1536
#define NH 64
#define ND 128
#define NTOPK 512

typedef float f32x4 __attribute__((ext_vector_type(4)));
typedef short bf16x8 __attribute__((ext_vector_type(8)));
typedef ushort u16x4 __attribute__((ext_vector_type(4)));
typedef ushort u16x8 __attribute__((ext_vector_type(8)));

__device__ __forceinline__ ushort f2bf(float x) {  // RNE f32->bf16
  uint32_t u = __float_as_uint(x);
  u += 0x7fffu + ((u >> 16) & 1u);
  return (ushort)(u >> 16);
}
__device__ __forceinline__ float bf2f(ushort u) {
  return __uint_as_float(((uint32_t)u) << 16);
}
__device__ __forceinline__ void gload_lds16(const void* g, void* l) {
  __builtin_amdgcn_global_load_lds(
      (const __attribute__((address_space(1))) uint32_t*)g,
      (__attribute__((address_space(3))) uint32_t*)l, 16, 0, 0);
}

// ---------------------------------------------------------------- rope table
__global__ void rope_table_k(const int* __restrict__ pos,
                             float* __restrict__ cost, float* __restrict__ sint) {
  int i = threadIdx.x;
  int t = blockIdx.x;
  if (i < 32) {
    double x = (double)(2 * i) / 64.0;
    double p = pow(10000.0, x);
    float p32 = (float)p;
    float invf = __fdiv_rn(1.0f, p32);
    float ang = __fmul_rn((float)pos[t], invf);
    cost[t * 32 + i] = (float)cos((double)ang);
    sint[t * 32 + i] = (float)sin((double)ang);
  }
}

// -------------------------------------------------------------- bf16 casts
__global__ __launch_bounds__(256)
void cast_bf16_k(const float* __restrict__ in, ushort* __restrict__ out, int n8) {
  int i = blockIdx.x * 256 + threadIdx.x;
  if (i >= n8) return;
  const f32x4* p = (const f32x4*)(in + (size_t)i * 8);
  f32x4 a = p[0], b = p[1];
  u16x8 r;
#pragma unroll
  for (int j = 0; j < 4; j++) r[j] = f2bf(a[j]);
#pragma unroll
  for (int j = 0; j < 4; j++) r[4 + j] = f2bf(b[j]);
  *(u16x8*)(out + (size_t)i * 8) = r;
}

// transpose-cast: in [K][N] f32 row-major -> out [N][K] bf16 row-major
__global__ __launch_bounds__(256)
void tcast_k(const float* __restrict__ in, ushort* __restrict__ out, int K, int N) {
  __shared__ ushort t[64][65];
  int tid = threadIdx.x;
  int n0 = blockIdx.x * 64, k0 = blockIdx.y * 64;
  int r = tid >> 4, c = (tid & 15) * 4;
#pragma unroll
  for (int rr = 0; rr < 64; rr += 16) {
    f32x4 v = *(const f32x4*)(in + (size_t)(k0 + rr + r) * N + n0 + c);
#pragma unroll
    for (int j = 0; j < 4; j++) t[rr + r][c + j] = f2bf(v[j]);
  }
  __syncthreads();
#pragma unroll
  for (int rr = 0; rr < 64; rr += 16) {
    int orow = rr + r;  // n-index within tile
    u16x4 w = {t[c + 0][orow], t[c + 1][orow], t[c + 2][orow], t[c + 3][orow]};
    *(u16x4*)(out + (size_t)(n0 + orow) * K + k0 + c) = w;
  }
}

// ------------------------------------------------------------- bf16 GEMM
// BM=128, BK=64, 4 waves (2x2), 4xFN 16x16x32 fragments per wave.
// A [M][K] bf16, Bt [N][K] bf16. OUTBF: write bf16 (z ignored), else f32 parts.
template <int BN, bool OUTBF>
__global__ __launch_bounds__(256)
void gemm_bf16_k(const ushort* __restrict__ A, const ushort* __restrict__ Bt,
                 void* __restrict__ Cv, int M, int N, int K, int kchunk) {
  constexpr int FN = BN / 32;
  __shared__ ushort As[128 * 64];
  __shared__ ushort Bs[BN * 64];
  int tid = threadIdx.x;
  int wave = tid >> 6, lane = tid & 63;
  int ln = lane & 15, lg = lane >> 4;
  int n0 = blockIdx.x * BN, m0 = blockIdx.y * 128;
  int k0 = blockIdx.z * kchunk;
  int wm = (wave >> 1) * 64, wn = (wave & 1) * (BN / 2);

  f32x4 acc[4][FN];
#pragma unroll
  for (int m = 0; m < 4; m++)
#pragma unroll
    for (int n = 0; n < FN; n++) acc[m][n] = {0.f, 0.f, 0.f, 0.f};

  for (int kt = 0; kt < kchunk; kt += 64) {
    int kk0 = k0 + kt;
#pragma unroll
    for (int c = 0; c < 4; c++) {  // A: 16KB = 4 calls x (4 waves x 1KB)
      int base = c * 4096 + wave * 1024;
      int o = base + lane * 16;
      int row = o >> 7, kb = (o & 127) >> 1;
      gload_lds16(A + (size_t)(m0 + row) * K + kk0 + kb, (char*)As + base);
    }
#pragma unroll
    for (int c = 0; c < BN / 32; c++) {  // B: BN*128B
      int base = c * 4096 + wave * 1024;
      int o = base + lane * 16;
      int row = o >> 7, kb = (o & 127) >> 1;
      gload_lds16(Bt + (size_t)(n0 + row) * K + kk0 + kb, (char*)Bs + base);
    }
    __syncthreads();
#pragma unroll
    for (int kk = 0; kk < 2; kk++) {
      bf16x8 af[4], bfr[FN];
#pragma unroll
      for (int m = 0; m < 4; m++)
        af[m] = *(const bf16x8*)(As + (wm + m * 16 + ln) * 64 + kk * 32 + lg * 8);
#pragma unroll
      for (int n = 0; n < FN; n++)
        bfr[n] = *(const bf16x8*)(Bs + (wn + n * 16 + ln) * 64 + kk * 32 + lg * 8);
#pragma unroll
      for (int m = 0; m < 4; m++)
#pragma unroll
        for (int n = 0; n < FN; n++)
          acc[m][n] = __builtin_amdgcn_mfma_f32_16x16x32_bf16(af[m], bfr[n],
                                                              acc[m][n], 0, 0, 0);
    }
    __syncthreads();
  }
  if constexpr (OUTBF) {
    ushort* Cb = (ushort*)Cv;
#pragma unroll
    for (int m = 0; m < 4; m++)
#pragma unroll
      for (int n = 0; n < FN; n++)
#pragma unroll
        for (int j = 0; j < 4; j++) {
          int row = m0 + wm + m * 16 + lg * 4 + j;
          int col = n0 + wn + n * 16 + ln;
          Cb[(size_t)row * N + col] = f2bf(acc[m][n][j]);
        }
  } else {
    float* C = (float*)Cv + (size_t)blockIdx.z * M * N;
#pragma unroll
    for (int m = 0; m < 4; m++)
#pragma unroll
      for (int n = 0; n < FN; n++)
#pragma unroll
        for (int j = 0; j < 4; j++) {
          int row = m0 + wm + m * 16 + lg * 4 + j;
          int col = n0 + wn + n * 16 + ln;
          C[(size_t)row * N + col] = acc[m][n][j];
        }
  }
}

// ---------------------------------------------------------- rope+fwht+quant
// One wave per 128-elem row: lane l owns elements l and l+64.
__device__ __forceinline__ void rope_fwht_quant(
    float v0, float v1, int l, int pos_t,
    const float* __restrict__ cost, const float* __restrict__ sint,
    uint8_t* __restrict__ out_bytes, float* __restrict__ out_scale) {
  float a = __shfl(v0, (2 * l) & 63, 64);      // x[2i]
  float b = __shfl(v0, (2 * l + 1) & 63, 64);  // x[2i+1]
  int fi = l & 31;
  float c = cost[pos_t * 32 + fi];
  float sn = sint[pos_t * 32 + fi];
  float r;
  if (l < 32)
    r = __fsub_rn(__fmul_rn(a, c), __fmul_rn(b, sn));
  else
    r = __fadd_rn(__fmul_rn(b, c), __fmul_rn(a, sn));
  v0 = r;  // elements 64..127 untouched by rope

#pragma unroll
  for (int m = 1; m < 64; m <<= 1) {  // FWHT Sylvester order
    float p0 = __shfl_xor(v0, m, 64);
    float p1 = __shfl_xor(v1, m, 64);
    bool up = (l & m) == 0;
    v0 = up ? __fadd_rn(v0, p0) : __fsub_rn(p0, v0);
    v1 = up ? __fadd_rn(v1, p1) : __fsub_rn(p1, v1);
  }
  {  // m = 64: pair (l, l+64) lane-local
    float A0 = v0, B0 = v1;
    v0 = __fadd_rn(A0, B0);
    v1 = __fsub_rn(A0, B0);
  }
  const float WS = 0.08838834764831843f;  // 128^-0.5
  v0 = __fmul_rn(v0, WS);
  v1 = __fmul_rn(v1, WS);

  float am = fmaxf(fabsf(v0), fabsf(v1));
#pragma unroll
  for (int m = 1; m < 64; m <<= 1) am = fmaxf(am, __shfl_xor(am, m, 64));
  am = fmaxf(am, 1e-4f);
  float ratio = __fdiv_rn(am, 448.0f);
  float l2 = (float)log2((double)ratio);
  float e = ceilf(l2);
  float sf = exp2f(e);
  float inv = __fdiv_rn(1.0f, sf);
  float q0 = __fmul_rn(v0, inv);
  float q1 = __fmul_rn(v1, inv);
  int b0 = __builtin_amdgcn_cvt_pk_fp8_f32(q0, q0, 0, false);
  int b1 = __builtin_amdgcn_cvt_pk_fp8_f32(q1, q1, 0, false);
  out_bytes[l] = (uint8_t)(b0 & 0xff);
  out_bytes[l + 64] = (uint8_t)(b1 & 0xff);
  if (l == 0) *out_scale = sf;
}

// --------------------------------------------------------------- k finalize
// kpart: [8][NT][192] f32, k columns 0..127
__global__ __launch_bounds__(256)
void k_finalize_k(const float* __restrict__ kpart, const float* __restrict__ gamma,
                  const float* __restrict__ beta, const float* __restrict__ cost,
                  const float* __restrict__ sint, uint8_t* __restrict__ kfp8,
                  float* __restrict__ kscale) {
  int l = threadIdx.x & 63;
  int row = blockIdx.x * 4 + (threadIdx.x >> 6);  // t
  float v0 = 0.0f, v1 = 0.0f;
#pragma unroll
  for (int p = 0; p < 8; p++) {
    v0 = __fadd_rn(v0, kpart[(size_t)p * (NT * 192) + row * 192 + l]);
    v1 = __fadd_rn(v1, kpart[(size_t)p * (NT * 192) + row * 192 + l + 64]);
  }
  float s = __fadd_rn(v0, v1);
#pragma unroll
  for (int m = 1; m < 64; m <<= 1) s = __fadd_rn(s, __shfl_xor(s, m, 64));
  float mu = __fmul_rn(s, 0.0078125f);
  float d0 = __fsub_rn(v0, mu), d1 = __fsub_rn(v1, mu);
  float vs = __fadd_rn(__fmul_rn(d0, d0), __fmul_rn(d1, d1));
#pragma unroll
  for (int m = 1; m < 64; m <<= 1) vs = __fadd_rn(vs, __shfl_xor(vs, m, 64));
  float var = __fmul_rn(vs, 0.0078125f);
  float rs = (float)(1.0 / sqrt((double)__fadd_rn(var, 1e-5f)));
  v0 = __fadd_rn(__fmul_rn(__fmul_rn(d0, rs), gamma[l]), beta[l]);
  v1 = __fadd_rn(__fmul_rn(__fmul_rn(d1, rs), gamma[l + 64]), beta[l + 64]);
  rope_fwht_quant(v0, v1, l, row, cost, sint, kfp8 + (size_t)row * ND, kscale + row);
}

// --------------------------------------------------------------- q finalize
__global__ __launch_bounds__(256)
void q_finalize_k(const ushort* __restrict__ qraw, const float* __restrict__ cost,
                  const float* __restrict__ sint, uint8_t* __restrict__ qfp8,
                  float* __restrict__ qscale) {
  int l = threadIdx.x & 63;
  int row = blockIdx.x * 4 + (threadIdx.x >> 6);  // t*64 + h
  int t = row >> 6;
  float v0 = bf2f(qraw[(size_t)row * ND + l]);
  float v1 = bf2f(qraw[(size_t)row * ND + l + 64]);
  rope_fwht_quant(v0, v1, l, t, cost, sint, qfp8 + (size_t)row * ND, qscale + row);
}

// ------------------------------------------------------------------ weights
// wpart = kpart columns 128..191
__global__ __launch_bounds__(256)
void weights_k(const float* __restrict__ kpart, const float* __restrict__ qscale,
               float* __restrict__ weights) {
  int i = blockIdx.x * 256 + threadIdx.x;  // t*64 + h
  int t = i >> 6, h = i & 63;
  float s = 0.0f;
#pragma unroll
  for (int p = 0; p < 8; p++)
    s = __fadd_rn(s, kpart[(size_t)p * (NT * 192) + t * 192 + 128 + h]);
  float w = __fmul_rn(s, 0.125f);
  w = __fmul_rn(w, qscale[i]);
  w = __fmul_rn(w, 0.08838834764831843f);
  weights[i] = w;
}

// ------------------------------------------------------------------- scores
__global__ __launch_bounds__(256)
void scores_k(const uint8_t* __restrict__ qfp8, const uint8_t* __restrict__ kfp8,
              const float* __restrict__ kscale, const float* __restrict__ weights,
              float* __restrict__ spart) {
  int t = blockIdx.x;
  int tid = threadIdx.x;
  int w = tid >> 6, lane = tid & 63;
  int lg = lane >> 4;
  int ln = lane & 15;

  float wj[4];
#pragma unroll
  for (int j = 0; j < 4; j++) wj[j] = weights[t * NH + w * 16 + lg * 4 + j];

  long afr[4];
  const uint8_t* qrow = qfp8 + (size_t)(t * NH + w * 16 + ln) * ND;
#pragma unroll
  for (int ks = 0; ks < 4; ks++) afr[ks] = *(const long*)(qrow + ks * 32 + lg * 8);

  for (int s0 = 0; s0 <= t; s0 += 64) {
    float psum[4];
#pragma unroll
    for (int sub = 0; sub < 4; sub++) {
      int s = s0 + sub * 16 + ln;
      const uint8_t* krow = kfp8 + (size_t)s * ND;
      f32x4 acc = {0.0f, 0.0f, 0.0f, 0.0f};
#pragma unroll
      for (int ks = 0; ks < 4; ks++) {
        long bfr = *(const long*)(krow + ks * 32 + lg * 8);
        acc = __builtin_amdgcn_mfma_f32_16x16x32_fp8_fp8(afr[ks], bfr, acc, 0, 0, 0);
      }
      float ksc = kscale[s];
      float p = 0.0f;
#pragma unroll
      for (int j = 0; j < 4; j++) {
        float logit = __fmul_rn(acc[j], ksc);
        p = fmaf(wj[j], fmaxf(logit, 0.0f), p);
      }
      psum[sub] = p;
    }
#pragma unroll
    for (int sub = 0; sub < 4; sub++) {
      float p = psum[sub];
      p += __shfl_xor(p, 16, 64);
      p += __shfl_xor(p, 32, 64);
      if (lg == 0)
        spart[((size_t)t * 4 + w) * NT + s0 + sub * 16 + ln] = p;
    }
  }
}

// -------------------------------------------------------------------- top-k
__global__ __launch_bounds__(256)
void topk_k(const float* __restrict__ spart, float* __restrict__ outv,
            float* __restrict__ outi) {
  __shared__ unsigned long long key[1024];
  int t = blockIdx.x, tid = threadIdx.x;
#pragma unroll
  for (int p = 0; p < 4; p++) {
    int s = tid + p * 256;
    float v;
    if (s <= t) {
      float a = spart[((size_t)t * 4 + 0) * NT + s];
      a = __fadd_rn(a, spart[((size_t)t * 4 + 1) * NT + s]);
      a = __fadd_rn(a, spart[((size_t)t * 4 + 2) * NT + s]);
      a = __fadd_rn(a, spart[((size_t)t * 4 + 3) * NT + s]);
      v = a;
    } else {
      v = -1e30f;
    }
    unsigned u = __float_as_uint(v);
    unsigned ou = (u & 0x80000000u) ? ~u : (u | 0x80000000u);
    key[s] = ((unsigned long long)ou << 32) | (unsigned)(~(unsigned)s);
  }
  for (int k = 2; k <= 1024; k <<= 1) {
    for (int j = k >> 1; j > 0; j >>= 1) {
      __syncthreads();
#pragma unroll
      for (int p = 0; p < 2; p++) {
        int i = tid + p * 256;
        int l = ((i & ~(j - 1)) << 1) | (i & (j - 1));
        int m = l + j;
        bool desc = ((l & k) == 0);
        unsigned long long a = key[l], b = key[m];
        if (desc ? (a < b) : (a > b)) {
          key[l] = b;
          key[m] = a;
        }
      }
    }
  }
  __syncthreads();
#pragma unroll
  for (int p = 0; p < 2; p++) {
    int r = tid + p * 256;
    unsigned long long kk = key[r];
    unsigned ou = (unsigned)(kk >> 32);
    unsigned u = (ou & 0x80000000u) ? (ou ^ 0x80000000u) : ~ou;
    unsigned idx = (~(unsigned)(kk & 0xffffffffu)) & 1023u;
    outv[(size_t)t * NTOPK + r] = __uint_as_float(u);
    outi[(size_t)t * NTOPK + r] = (float)idx;
  }
}

// ------------------------------------------------------------------- launch
extern "C" void kernel_launch(void* const* d_in, const int* in_sizes, int n_in,
                              void* d_out, int out_size, void* d_ws, size_t ws_size,
                              hipStream_t stream) {
  const float* hidden = (const float*)d_in[0];
  const float* q_lora = (const float*)d_in[1];
  const int* positions = (const int*)d_in[2];
  const float* wq_b = (const float*)d_in[3];
  const float* wk = (const float*)d_in[4];
  const float* w_proj = (const float*)d_in[5];
  const float* ln_g = (const float*)d_in[6];
  const float* ln_b = (const float*)d_in[7];
  float* out = (float*)d_out;

  // ---- workspace layout (phase-aliased union region first; peak ~60.7 MB)
  char* u0 = (char*)d_ws;
  // phase A (hidden-proj): hidden_bf [1024][7168], wkp_t [192][7168]
  ushort* hiddenb = (ushort*)u0;                       // 14,680,064 B
  ushort* wkpt = (ushort*)(u0 + 14680064);             //  2,752,512 B
  // phase B (q): wqb_t [8192][1536], qlora_bf [1024][1536]
  ushort* wqbt = (ushort*)u0;                          // 25,165,824 B
  ushort* qlorab = (ushort*)(u0 + 25165824);           //  3,145,728 B
  // phase C (scores): spart [4][1024][1024] f32
  float* spart = (float*)u0;                           // 16,777,216 B
  char* p = u0 + 28311552;
  ushort* qrawb = (ushort*)p;  p += 16777216;          // [1024*64][128] bf16
  float* kpart = (float*)p;    p += 6291456;           // [8][1024][192] f32
  float* cost = (float*)p;     p += 131072;
  float* sint = (float*)p;     p += 131072;
  float* kscale = (float*)p;   p += 4096;
  float* qscale = (float*)p;   p += 262144;
  float* weights = (float*)p;  p += 262144;
  uint8_t* kfp8 = (uint8_t*)p; p += 131072;
  uint8_t* qfp8 = (uint8_t*)p; p += 8388608;

  rope_table_k<<<NT, 64, 0, stream>>>(positions, cost, sint);

  // phase A: k + weights projections (combined B = [wk | w_proj], N=192)
  cast_bf16_k<<<NT * NHID / 8 / 256, 256, 0, stream>>>(hidden, hiddenb, NT * NHID / 8);
  tcast_k<<<dim3(2, 112), 256, 0, stream>>>(wk, wkpt, NHID, ND);
  tcast_k<<<dim3(1, 112), 256, 0, stream>>>(w_proj, wkpt + 128 * NHID, NHID, NH);
  gemm_bf16_k<64, false><<<dim3(3, 8, 8), 256, 0, stream>>>(
      hiddenb, wkpt, kpart, NT, 192, NHID, 896);

  // phase B: q projection (overwrites phase-A cast buffers)
  cast_bf16_k<<<NT * NR / 8 / 256, 256, 0, stream>>>(q_lora, qlorab, NT * NR / 8);
  tcast_k<<<dim3(128, 24), 256, 0, stream>>>(wq_b, wqbt, NR, NH * ND);
  gemm_bf16_k<128, true><<<dim3(64, 8, 1), 256, 0, stream>>>(
      qlorab, wqbt, qrawb, NT, NH * ND, NR, NR);

  k_finalize_k<<<NT / 4, 256, 0, stream>>>(kpart, ln_g, ln_b, cost, sint, kfp8, kscale);
  q_finalize_k<<<NT * NH / 4, 256, 0, stream>>>(qrawb, cost, sint, qfp8, qscale);
  weights_k<<<NT * NH / 256, 256, 0, stream>>>(kpart, qscale, weights);

  // phase C: scores (overwrites phase-B cast buffers) + top-k
  scores_k<<<NT, 256, 0, stream>>>(qfp8, kfp8, kscale, weights, spart);
  topk_k<<<NT, 256, 0, stream>>>(spart, out, out + (size_t)NT * NTOPK);
}

// Round 3
// 225.666 us; speedup vs baseline: 2.6817x; 1.0151x over previous
//
#include <hip/hip_runtime.h>
#include <cstdint>
#include <cmath>

// Problem constants (T=1024, HID=7168, R=1536, H=64, D=128, RD=64, TOPK=512)
#define NT 1024
#define NHID 7168
#define NR 1536
#define NH 64
#define ND 128
#define NTOPK 512

typedef float f32x4 __attribute__((ext_vector_type(4)));
typedef short bf16x8 __attribute__((ext_vector_type(8)));
typedef ushort u16x4 __attribute__((ext_vector_type(4)));
typedef ushort u16x8 __attribute__((ext_vector_type(8)));

__device__ __forceinline__ ushort f2bf(float x) {  // RNE f32->bf16
  uint32_t u = __float_as_uint(x);
  u += 0x7fffu + ((u >> 16) & 1u);
  return (ushort)(u >> 16);
}
__device__ __forceinline__ float bf2f(ushort u) {
  return __uint_as_float(((uint32_t)u) << 16);
}
__device__ __forceinline__ void gload_lds16(const void* g, void* l) {
  __builtin_amdgcn_global_load_lds(
      (const __attribute__((address_space(1))) uint32_t*)g,
      (__attribute__((address_space(3))) uint32_t*)l, 16, 0, 0);
}

// ---------------------------------------------------------------- rope table
__global__ void rope_table_k(const int* __restrict__ pos,
                             float* __restrict__ cost, float* __restrict__ sint) {
  int i = threadIdx.x;
  int t = blockIdx.x;
  if (i < 32) {
    double x = (double)(2 * i) / 64.0;
    double p = pow(10000.0, x);
    float p32 = (float)p;
    float invf = __fdiv_rn(1.0f, p32);
    float ang = __fmul_rn((float)pos[t], invf);
    cost[t * 32 + i] = (float)cos((double)ang);
    sint[t * 32 + i] = (float)sin((double)ang);
  }
}

// -------------------------------------------------------------- bf16 casts
__global__ __launch_bounds__(256)
void cast_bf16_k(const float* __restrict__ in, ushort* __restrict__ out, int n8) {
  int i = blockIdx.x * 256 + threadIdx.x;
  if (i >= n8) return;
  const f32x4* p = (const f32x4*)(in + (size_t)i * 8);
  f32x4 a = p[0], b = p[1];
  u16x8 r;
#pragma unroll
  for (int j = 0; j < 4; j++) r[j] = f2bf(a[j]);
#pragma unroll
  for (int j = 0; j < 4; j++) r[4 + j] = f2bf(b[j]);
  *(u16x8*)(out + (size_t)i * 8) = r;
}

// transpose-cast: in [K][N] f32 row-major -> out [N][K] bf16 row-major
__global__ __launch_bounds__(256)
void tcast_k(const float* __restrict__ in, ushort* __restrict__ out, int K, int N) {
  __shared__ ushort t[64][65];
  int tid = threadIdx.x;
  int n0 = blockIdx.x * 64, k0 = blockIdx.y * 64;
  int r = tid >> 4, c = (tid & 15) * 4;
#pragma unroll
  for (int rr = 0; rr < 64; rr += 16) {
    f32x4 v = *(const f32x4*)(in + (size_t)(k0 + rr + r) * N + n0 + c);
#pragma unroll
    for (int j = 0; j < 4; j++) t[rr + r][c + j] = f2bf(v[j]);
  }
  __syncthreads();
#pragma unroll
  for (int rr = 0; rr < 64; rr += 16) {
    int orow = rr + r;  // n-index within tile
    u16x4 w = {t[c + 0][orow], t[c + 1][orow], t[c + 2][orow], t[c + 3][orow]};
    *(u16x4*)(out + (size_t)(n0 + orow) * K + k0 + c) = w;
  }
}

// ------------------------------------------------------------- bf16 GEMM
// BM=128, BK=64, 4 waves (2x2), 4xFN 16x16x32 fragments per wave.
// A [M][K] bf16, Bt [N][K] bf16. OUTBF: write bf16 (z ignored), else f32 parts.
template <int BN, bool OUTBF>
__global__ __launch_bounds__(256)
void gemm_bf16_k(const ushort* __restrict__ A, const ushort* __restrict__ Bt,
                 void* __restrict__ Cv, int M, int N, int K, int kchunk) {
  constexpr int FN = BN / 32;
  __shared__ ushort As[128 * 64];
  __shared__ ushort Bs[BN * 64];
  int tid = threadIdx.x;
  int wave = tid >> 6, lane = tid & 63;
  int ln = lane & 15, lg = lane >> 4;
  int n0 = blockIdx.x * BN, m0 = blockIdx.y * 128;
  int k0 = blockIdx.z * kchunk;
  int wm = (wave >> 1) * 64, wn = (wave & 1) * (BN / 2);

  f32x4 acc[4][FN];
#pragma unroll
  for (int m = 0; m < 4; m++)
#pragma unroll
    for (int n = 0; n < FN; n++) acc[m][n] = {0.f, 0.f, 0.f, 0.f};

  for (int kt = 0; kt < kchunk; kt += 64) {
    int kk0 = k0 + kt;
#pragma unroll
    for (int c = 0; c < 4; c++) {  // A: 16KB = 4 calls x (4 waves x 1KB)
      int base = c * 4096 + wave * 1024;
      int o = base + lane * 16;
      int row = o >> 7, kb = (o & 127) >> 1;
      gload_lds16(A + (size_t)(m0 + row) * K + kk0 + kb, (char*)As + base);
    }
#pragma unroll
    for (int c = 0; c < BN / 32; c++) {  // B: BN*128B
      int base = c * 4096 + wave * 1024;
      int o = base + lane * 16;
      int row = o >> 7, kb = (o & 127) >> 1;
      gload_lds16(Bt + (size_t)(n0 + row) * K + kk0 + kb, (char*)Bs + base);
    }
    __syncthreads();
#pragma unroll
    for (int kk = 0; kk < 2; kk++) {
      bf16x8 af[4], bfr[FN];
#pragma unroll
      for (int m = 0; m < 4; m++)
        af[m] = *(const bf16x8*)(As + (wm + m * 16 + ln) * 64 + kk * 32 + lg * 8);
#pragma unroll
      for (int n = 0; n < FN; n++)
        bfr[n] = *(const bf16x8*)(Bs + (wn + n * 16 + ln) * 64 + kk * 32 + lg * 8);
#pragma unroll
      for (int m = 0; m < 4; m++)
#pragma unroll
        for (int n = 0; n < FN; n++)
          acc[m][n] = __builtin_amdgcn_mfma_f32_16x16x32_bf16(af[m], bfr[n],
                                                              acc[m][n], 0, 0, 0);
    }
    __syncthreads();
  }
  if constexpr (OUTBF) {
    ushort* Cb = (ushort*)Cv;
#pragma unroll
    for (int m = 0; m < 4; m++)
#pragma unroll
      for (int n = 0; n < FN; n++)
#pragma unroll
        for (int j = 0; j < 4; j++) {
          int row = m0 + wm + m * 16 + lg * 4 + j;
          int col = n0 + wn + n * 16 + ln;
          Cb[(size_t)row * N + col] = f2bf(acc[m][n][j]);
        }
  } else {
    float* C = (float*)Cv + (size_t)blockIdx.z * M * N;
#pragma unroll
    for (int m = 0; m < 4; m++)
#pragma unroll
      for (int n = 0; n < FN; n++)
#pragma unroll
        for (int j = 0; j < 4; j++) {
          int row = m0 + wm + m * 16 + lg * 4 + j;
          int col = n0 + wn + n * 16 + ln;
          C[(size_t)row * N + col] = acc[m][n][j];
        }
  }
}

// ---------------------------------------------------------- rope+fwht+quant
// One wave per 128-elem row: lane l owns elements l and l+64.
__device__ __forceinline__ void rope_fwht_quant(
    float v0, float v1, int l, int pos_t,
    const float* __restrict__ cost, const float* __restrict__ sint,
    uint8_t* __restrict__ out_bytes, float* __restrict__ out_scale) {
  float a = __shfl(v0, (2 * l) & 63, 64);      // x[2i]
  float b = __shfl(v0, (2 * l + 1) & 63, 64);  // x[2i+1]
  int fi = l & 31;
  float c = cost[pos_t * 32 + fi];
  float sn = sint[pos_t * 32 + fi];
  float r;
  if (l < 32)
    r = __fsub_rn(__fmul_rn(a, c), __fmul_rn(b, sn));
  else
    r = __fadd_rn(__fmul_rn(b, c), __fmul_rn(a, sn));
  v0 = r;  // elements 64..127 untouched by rope

#pragma unroll
  for (int m = 1; m < 64; m <<= 1) {  // FWHT Sylvester order
    float p0 = __shfl_xor(v0, m, 64);
    float p1 = __shfl_xor(v1, m, 64);
    bool up = (l & m) == 0;
    v0 = up ? __fadd_rn(v0, p0) : __fsub_rn(p0, v0);
    v1 = up ? __fadd_rn(v1, p1) : __fsub_rn(p1, v1);
  }
  {  // m = 64: pair (l, l+64) lane-local
    float A0 = v0, B0 = v1;
    v0 = __fadd_rn(A0, B0);
    v1 = __fsub_rn(A0, B0);
  }
  const float WS = 0.08838834764831843f;  // 128^-0.5
  v0 = __fmul_rn(v0, WS);
  v1 = __fmul_rn(v1, WS);

  float am = fmaxf(fabsf(v0), fabsf(v1));
#pragma unroll
  for (int m = 1; m < 64; m <<= 1) am = fmaxf(am, __shfl_xor(am, m, 64));
  am = fmaxf(am, 1e-4f);
  float ratio = __fdiv_rn(am, 448.0f);
  float l2 = (float)log2((double)ratio);
  float e = ceilf(l2);
  float sf = exp2f(e);
  float inv = __fdiv_rn(1.0f, sf);
  float q0 = __fmul_rn(v0, inv);
  float q1 = __fmul_rn(v1, inv);
  int b0 = __builtin_amdgcn_cvt_pk_fp8_f32(q0, q0, 0, false);
  int b1 = __builtin_amdgcn_cvt_pk_fp8_f32(q1, q1, 0, false);
  out_bytes[l] = (uint8_t)(b0 & 0xff);
  out_bytes[l + 64] = (uint8_t)(b1 & 0xff);
  if (l == 0) *out_scale = sf;
}

// --------------------------------------------------------------- k finalize
// kpart: [8][NT][192] f32, k columns 0..127
__global__ __launch_bounds__(256)
void k_finalize_k(const float* __restrict__ kpart, const float* __restrict__ gamma,
                  const float* __restrict__ beta, const float* __restrict__ cost,
                  const float* __restrict__ sint, uint8_t* __restrict__ kfp8,
                  float* __restrict__ kscale) {
  int l = threadIdx.x & 63;
  int row = blockIdx.x * 4 + (threadIdx.x >> 6);  // t
  float v0 = 0.0f, v1 = 0.0f;
#pragma unroll
  for (int p = 0; p < 8; p++) {
    v0 = __fadd_rn(v0, kpart[(size_t)p * (NT * 192) + row * 192 + l]);
    v1 = __fadd_rn(v1, kpart[(size_t)p * (NT * 192) + row * 192 + l + 64]);
  }
  float s = __fadd_rn(v0, v1);
#pragma unroll
  for (int m = 1; m < 64; m <<= 1) s = __fadd_rn(s, __shfl_xor(s, m, 64));
  float mu = __fmul_rn(s, 0.0078125f);
  float d0 = __fsub_rn(v0, mu), d1 = __fsub_rn(v1, mu);
  float vs = __fadd_rn(__fmul_rn(d0, d0), __fmul_rn(d1, d1));
#pragma unroll
  for (int m = 1; m < 64; m <<= 1) vs = __fadd_rn(vs, __shfl_xor(vs, m, 64));
  float var = __fmul_rn(vs, 0.0078125f);
  float rs = (float)(1.0 / sqrt((double)__fadd_rn(var, 1e-5f)));
  v0 = __fadd_rn(__fmul_rn(__fmul_rn(d0, rs), gamma[l]), beta[l]);
  v1 = __fadd_rn(__fmul_rn(__fmul_rn(d1, rs), gamma[l + 64]), beta[l + 64]);
  rope_fwht_quant(v0, v1, l, row, cost, sint, kfp8 + (size_t)row * ND, kscale + row);
}

// --------------------------------------------------------------- q finalize
__global__ __launch_bounds__(256)
void q_finalize_k(const ushort* __restrict__ qraw, const float* __restrict__ cost,
                  const float* __restrict__ sint, uint8_t* __restrict__ qfp8,
                  float* __restrict__ qscale) {
  int l = threadIdx.x & 63;
  int row = blockIdx.x * 4 + (threadIdx.x >> 6);  // t*64 + h
  int t = row >> 6;
  float v0 = bf2f(qraw[(size_t)row * ND + l]);
  float v1 = bf2f(qraw[(size_t)row * ND + l + 64]);
  rope_fwht_quant(v0, v1, l, t, cost, sint, qfp8 + (size_t)row * ND, qscale + row);
}

// ------------------------------------------------------------------ weights
// wpart = kpart columns 128..191
__global__ __launch_bounds__(256)
void weights_k(const float* __restrict__ kpart, const float* __restrict__ qscale,
               float* __restrict__ weights) {
  int i = blockIdx.x * 256 + threadIdx.x;  // t*64 + h
  int t = i >> 6, h = i & 63;
  float s = 0.0f;
#pragma unroll
  for (int p = 0; p < 8; p++)
    s = __fadd_rn(s, kpart[(size_t)p * (NT * 192) + t * 192 + 128 + h]);
  float w = __fmul_rn(s, 0.125f);
  w = __fmul_rn(w, qscale[i]);
  w = __fmul_rn(w, 0.08838834764831843f);
  weights[i] = w;
}

// ------------------------------------------------------------------- scores
// One block per (t, 128-wide s-chunk) pair; 4608 blocks total.
// Wave w handles heads 16w..16w+15; 8 independent s-subs of 16 each.
// kscale is factored OUT (applied in topk; exact for pow2 scales).
__global__ __launch_bounds__(256)
void scores_k(const uint8_t* __restrict__ qfp8, const uint8_t* __restrict__ kfp8,
              const float* __restrict__ weights, float* __restrict__ spart) {
  int b = blockIdx.x;
  // decode (t, chunk): group a (t in [128a,128a+128)) starts at 64a(a+1)
  int a = 0;
  while (a < 7 && b >= 64 * (a + 1) * (a + 2)) a++;
  int r = b - 64 * a * (a + 1);
  int t = 128 * a + r / (a + 1);
  int chunk = r % (a + 1);
  int sbase = chunk * 128;

  int tid = threadIdx.x;
  int w = tid >> 6, lane = tid & 63;
  int lg = lane >> 4;  // k-slice / acc row-group
  int ln = lane & 15;  // A row (head) / B col (s)

  float wj[4];
#pragma unroll
  for (int j = 0; j < 4; j++) wj[j] = weights[t * NH + w * 16 + lg * 4 + j];

  long afr[4];
  const uint8_t* qrow = qfp8 + (size_t)(t * NH + w * 16 + ln) * ND;
#pragma unroll
  for (int ks = 0; ks < 4; ks++) afr[ks] = *(const long*)(qrow + ks * 32 + lg * 8);

  f32x4 acc[8];
#pragma unroll
  for (int sub = 0; sub < 8; sub++) acc[sub] = {0.f, 0.f, 0.f, 0.f};
#pragma unroll
  for (int ks = 0; ks < 4; ks++) {  // 8 independent chains of depth 4
#pragma unroll
    for (int sub = 0; sub < 8; sub++) {
      int s = sbase + sub * 16 + ln;
      long bfr = *(const long*)(kfp8 + (size_t)s * ND + ks * 32 + lg * 8);
      acc[sub] = __builtin_amdgcn_mfma_f32_16x16x32_fp8_fp8(afr[ks], bfr,
                                                            acc[sub], 0, 0, 0);
    }
  }
#pragma unroll
  for (int sub = 0; sub < 8; sub++) {
    float p = 0.0f;
#pragma unroll
    for (int j = 0; j < 4; j++) p = fmaf(wj[j], fmaxf(acc[sub][j], 0.0f), p);
    p += __shfl_xor(p, 16, 64);
    p += __shfl_xor(p, 32, 64);
    if (lg == 0)
      spart[((size_t)t * 4 + w) * NT + sbase + sub * 16 + ln] = p;
  }
}

// -------------------------------------------------------------------- top-k
__global__ __launch_bounds__(256)
void topk_k(const float* __restrict__ spart, const float* __restrict__ kscale,
            float* __restrict__ outv, float* __restrict__ outi) {
  __shared__ unsigned long long key[1024];
  int t = blockIdx.x, tid = threadIdx.x;
#pragma unroll
  for (int p = 0; p < 4; p++) {
    int s = tid + p * 256;
    float v;
    if (s <= t) {
      float a = spart[((size_t)t * 4 + 0) * NT + s];
      a = __fadd_rn(a, spart[((size_t)t * 4 + 1) * NT + s]);
      a = __fadd_rn(a, spart[((size_t)t * 4 + 2) * NT + s]);
      a = __fadd_rn(a, spart[((size_t)t * 4 + 3) * NT + s]);
      v = __fmul_rn(a, kscale[s]);  // exact pow2 factoring
    } else {
      v = -1e30f;
    }
    unsigned u = __float_as_uint(v);
    unsigned ou = (u & 0x80000000u) ? ~u : (u | 0x80000000u);
    key[s] = ((unsigned long long)ou << 32) | (unsigned)(~(unsigned)s);
  }
  for (int k = 2; k <= 1024; k <<= 1) {
    for (int j = k >> 1; j > 0; j >>= 1) {
      __syncthreads();
#pragma unroll
      for (int p = 0; p < 2; p++) {
        int i = tid + p * 256;
        int l = ((i & ~(j - 1)) << 1) | (i & (j - 1));
        int m = l + j;
        bool desc = ((l & k) == 0);
        unsigned long long a = key[l], b = key[m];
        if (desc ? (a < b) : (a > b)) {
          key[l] = b;
          key[m] = a;
        }
      }
    }
  }
  __syncthreads();
#pragma unroll
  for (int p = 0; p < 2; p++) {
    int r = tid + p * 256;
    unsigned long long kk = key[r];
    unsigned ou = (unsigned)(kk >> 32);
    unsigned u = (ou & 0x80000000u) ? (ou ^ 0x80000000u) : ~ou;
    unsigned idx = (~(unsigned)(kk & 0xffffffffu)) & 1023u;
    outv[(size_t)t * NTOPK + r] = __uint_as_float(u);
    outi[(size_t)t * NTOPK + r] = (float)idx;
  }
}

// ------------------------------------------------------------------- launch
extern "C" void kernel_launch(void* const* d_in, const int* in_sizes, int n_in,
                              void* d_out, int out_size, void* d_ws, size_t ws_size,
                              hipStream_t stream) {
  const float* hidden = (const float*)d_in[0];
  const float* q_lora = (const float*)d_in[1];
  const int* positions = (const int*)d_in[2];
  const float* wq_b = (const float*)d_in[3];
  const float* wk = (const float*)d_in[4];
  const float* w_proj = (const float*)d_in[5];
  const float* ln_g = (const float*)d_in[6];
  const float* ln_b = (const float*)d_in[7];
  float* out = (float*)d_out;

  // ---- workspace layout (phase-aliased union region first; peak ~60.7 MB)
  char* u0 = (char*)d_ws;
  // phase A (hidden-proj): hidden_bf [1024][7168], wkp_t [192][7168]
  ushort* hiddenb = (ushort*)u0;                       // 14,680,064 B
  ushort* wkpt = (ushort*)(u0 + 14680064);             //  2,752,512 B
  // phase B (q): wqb_t [8192][1536], qlora_bf [1024][1536]
  ushort* wqbt = (ushort*)u0;                          // 25,165,824 B
  ushort* qlorab = (ushort*)(u0 + 25165824);           //  3,145,728 B
  // phase C (scores): spart [4][1024][1024] f32
  float* spart = (float*)u0;                           // 16,777,216 B
  char* p = u0 + 28311552;
  ushort* qrawb = (ushort*)p;  p += 16777216;          // [1024*64][128] bf16
  float* kpart = (float*)p;    p += 6291456;           // [8][1024][192] f32
  float* cost = (float*)p;     p += 131072;
  float* sint = (float*)p;     p += 131072;
  float* kscale = (float*)p;   p += 4096;
  float* qscale = (float*)p;   p += 262144;
  float* weights = (float*)p;  p += 262144;
  uint8_t* kfp8 = (uint8_t*)p; p += 131072;
  uint8_t* qfp8 = (uint8_t*)p; p += 8388608;

  rope_table_k<<<NT, 64, 0, stream>>>(positions, cost, sint);

  // phase A: k + weights projections (combined B = [wk | w_proj], N=192)
  cast_bf16_k<<<NT * NHID / 8 / 256, 256, 0, stream>>>(hidden, hiddenb, NT * NHID / 8);
  tcast_k<<<dim3(2, 112), 256, 0, stream>>>(wk, wkpt, NHID, ND);
  tcast_k<<<dim3(1, 112), 256, 0, stream>>>(w_proj, wkpt + 128 * NHID, NHID, NH);
  gemm_bf16_k<64, false><<<dim3(3, 8, 8), 256, 0, stream>>>(
      hiddenb, wkpt, kpart, NT, 192, NHID, 896);

  // phase B: q projection (overwrites phase-A cast buffers)
  cast_bf16_k<<<NT * NR / 8 / 256, 256, 0, stream>>>(q_lora, qlorab, NT * NR / 8);
  tcast_k<<<dim3(128, 24), 256, 0, stream>>>(wq_b, wqbt, NR, NH * ND);
  gemm_bf16_k<128, true><<<dim3(64, 8, 1), 256, 0, stream>>>(
      qlorab, wqbt, qrawb, NT, NH * ND, NR, NR);

  k_finalize_k<<<NT / 4, 256, 0, stream>>>(kpart, ln_g, ln_b, cost, sint, kfp8, kscale);
  q_finalize_k<<<NT * NH / 4, 256, 0, stream>>>(qrawb, cost, sint, qfp8, qscale);
  weights_k<<<NT * NH / 256, 256, 0, stream>>>(kpart, qscale, weights);

  // phase C: scores (overwrites phase-B cast buffers) + top-k
  scores_k<<<4608, 256, 0, stream>>>(qfp8, kfp8, weights, spart);
  topk_k<<<NT, 256, 0, stream>>>(spart, kscale, out, out + (size_t)NT * NTOPK);
}

// Round 4
// 167.160 us; speedup vs baseline: 3.6203x; 1.3500x over previous
//
#include <hip/hip_runtime.h>
#include <cstdint>
#include <cmath>

// Problem constants (T=1024, HID=7168, R=1536, H=64, D=128, RD=64, TOPK=512)
#define NT 1024
#define NHID 7168
#define NR 1536
#define NH 64
#define ND 128
#define NTOPK 512
#define TTILE 4

typedef float f32x4 __attribute__((ext_vector_type(4)));
typedef short bf16x8 __attribute__((ext_vector_type(8)));
typedef ushort u16x4 __attribute__((ext_vector_type(4)));
typedef ushort u16x8 __attribute__((ext_vector_type(8)));

__device__ __forceinline__ ushort f2bf(float x) {  // RNE f32->bf16
  uint32_t u = __float_as_uint(x);
  u += 0x7fffu + ((u >> 16) & 1u);
  return (ushort)(u >> 16);
}
__device__ __forceinline__ float bf2f(ushort u) {
  return __uint_as_float(((uint32_t)u) << 16);
}
__device__ __forceinline__ void gload_lds16(const void* g, void* l) {
  __builtin_amdgcn_global_load_lds(
      (const __attribute__((address_space(1))) uint32_t*)g,
      (__attribute__((address_space(3))) uint32_t*)l, 16, 0, 0);
}

// ---------------------------------------------------------------- rope table
__global__ void rope_table_k(const int* __restrict__ pos,
                             float* __restrict__ cost, float* __restrict__ sint) {
  int i = threadIdx.x;
  int t = blockIdx.x;
  if (i < 32) {
    double x = (double)(2 * i) / 64.0;
    double p = pow(10000.0, x);
    float p32 = (float)p;
    float invf = __fdiv_rn(1.0f, p32);
    float ang = __fmul_rn((float)pos[t], invf);
    cost[t * 32 + i] = (float)cos((double)ang);
    sint[t * 32 + i] = (float)sin((double)ang);
  }
}

// -------------------------------------------------------------- bf16 casts
__global__ __launch_bounds__(256)
void cast_bf16_k(const float* __restrict__ in, ushort* __restrict__ out, int n8) {
  int i = blockIdx.x * 256 + threadIdx.x;
  if (i >= n8) return;
  const f32x4* p = (const f32x4*)(in + (size_t)i * 8);
  f32x4 a = p[0], b = p[1];
  u16x8 r;
#pragma unroll
  for (int j = 0; j < 4; j++) r[j] = f2bf(a[j]);
#pragma unroll
  for (int j = 0; j < 4; j++) r[4 + j] = f2bf(b[j]);
  *(u16x8*)(out + (size_t)i * 8) = r;
}

// transpose-cast: in [K][N] f32 row-major -> out [N][K] bf16 row-major
__global__ __launch_bounds__(256)
void tcast_k(const float* __restrict__ in, ushort* __restrict__ out, int K, int N) {
  __shared__ ushort t[64][65];
  int tid = threadIdx.x;
  int n0 = blockIdx.x * 64, k0 = blockIdx.y * 64;
  int r = tid >> 4, c = (tid & 15) * 4;
#pragma unroll
  for (int rr = 0; rr < 64; rr += 16) {
    f32x4 v = *(const f32x4*)(in + (size_t)(k0 + rr + r) * N + n0 + c);
#pragma unroll
    for (int j = 0; j < 4; j++) t[rr + r][c + j] = f2bf(v[j]);
  }
  __syncthreads();
#pragma unroll
  for (int rr = 0; rr < 64; rr += 16) {
    int orow = rr + r;  // n-index within tile
    u16x4 w = {t[c + 0][orow], t[c + 1][orow], t[c + 2][orow], t[c + 3][orow]};
    *(u16x4*)(out + (size_t)(n0 + orow) * K + k0 + c) = w;
  }
}

// ------------------------------------------------------------- bf16 GEMM
// BM=128, BK=64, 4 waves (2x2), 4xFN 16x16x32 fragments per wave.
// A [M][K] bf16, Bt [N][K] bf16. OUTBF: write bf16 (z ignored), else f32 parts.
template <int BN, bool OUTBF>
__global__ __launch_bounds__(256)
void gemm_bf16_k(const ushort* __restrict__ A, const ushort* __restrict__ Bt,
                 void* __restrict__ Cv, int M, int N, int K, int kchunk) {
  constexpr int FN = BN / 32;
  __shared__ ushort As[128 * 64];
  __shared__ ushort Bs[BN * 64];
  int tid = threadIdx.x;
  int wave = tid >> 6, lane = tid & 63;
  int ln = lane & 15, lg = lane >> 4;
  int n0 = blockIdx.x * BN, m0 = blockIdx.y * 128;
  int k0 = blockIdx.z * kchunk;
  int wm = (wave >> 1) * 64, wn = (wave & 1) * (BN / 2);

  f32x4 acc[4][FN];
#pragma unroll
  for (int m = 0; m < 4; m++)
#pragma unroll
    for (int n = 0; n < FN; n++) acc[m][n] = {0.f, 0.f, 0.f, 0.f};

  for (int kt = 0; kt < kchunk; kt += 64) {
    int kk0 = k0 + kt;
#pragma unroll
    for (int c = 0; c < 4; c++) {  // A: 16KB = 4 calls x (4 waves x 1KB)
      int base = c * 4096 + wave * 1024;
      int o = base + lane * 16;
      int row = o >> 7, kb = (o & 127) >> 1;
      gload_lds16(A + (size_t)(m0 + row) * K + kk0 + kb, (char*)As + base);
    }
#pragma unroll
    for (int c = 0; c < BN / 32; c++) {  // B: BN*128B
      int base = c * 4096 + wave * 1024;
      int o = base + lane * 16;
      int row = o >> 7, kb = (o & 127) >> 1;
      gload_lds16(Bt + (size_t)(n0 + row) * K + kk0 + kb, (char*)Bs + base);
    }
    __syncthreads();
#pragma unroll
    for (int kk = 0; kk < 2; kk++) {
      bf16x8 af[4], bfr[FN];
#pragma unroll
      for (int m = 0; m < 4; m++)
        af[m] = *(const bf16x8*)(As + (wm + m * 16 + ln) * 64 + kk * 32 + lg * 8);
#pragma unroll
      for (int n = 0; n < FN; n++)
        bfr[n] = *(const bf16x8*)(Bs + (wn + n * 16 + ln) * 64 + kk * 32 + lg * 8);
#pragma unroll
      for (int m = 0; m < 4; m++)
#pragma unroll
        for (int n = 0; n < FN; n++)
          acc[m][n] = __builtin_amdgcn_mfma_f32_16x16x32_bf16(af[m], bfr[n],
                                                              acc[m][n], 0, 0, 0);
    }
    __syncthreads();
  }
  if constexpr (OUTBF) {
    ushort* Cb = (ushort*)Cv;
#pragma unroll
    for (int m = 0; m < 4; m++)
#pragma unroll
      for (int n = 0; n < FN; n++)
#pragma unroll
        for (int j = 0; j < 4; j++) {
          int row = m0 + wm + m * 16 + lg * 4 + j;
          int col = n0 + wn + n * 16 + ln;
          Cb[(size_t)row * N + col] = f2bf(acc[m][n][j]);
        }
  } else {
    float* C = (float*)Cv + (size_t)blockIdx.z * M * N;
#pragma unroll
    for (int m = 0; m < 4; m++)
#pragma unroll
      for (int n = 0; n < FN; n++)
#pragma unroll
        for (int j = 0; j < 4; j++) {
          int row = m0 + wm + m * 16 + lg * 4 + j;
          int col = n0 + wn + n * 16 + ln;
          C[(size_t)row * N + col] = acc[m][n][j];
        }
  }
}

// ---------------------------------------------------------- rope+fwht+quant
// One wave per 128-elem row: lane l owns elements l and l+64.
__device__ __forceinline__ void rope_fwht_quant(
    float v0, float v1, int l, int pos_t,
    const float* __restrict__ cost, const float* __restrict__ sint,
    uint8_t* __restrict__ out_bytes, float* __restrict__ out_scale) {
  float a = __shfl(v0, (2 * l) & 63, 64);      // x[2i]
  float b = __shfl(v0, (2 * l + 1) & 63, 64);  // x[2i+1]
  int fi = l & 31;
  float c = cost[pos_t * 32 + fi];
  float sn = sint[pos_t * 32 + fi];
  float r;
  if (l < 32)
    r = __fsub_rn(__fmul_rn(a, c), __fmul_rn(b, sn));
  else
    r = __fadd_rn(__fmul_rn(b, c), __fmul_rn(a, sn));
  v0 = r;  // elements 64..127 untouched by rope

#pragma unroll
  for (int m = 1; m < 64; m <<= 1) {  // FWHT Sylvester order
    float p0 = __shfl_xor(v0, m, 64);
    float p1 = __shfl_xor(v1, m, 64);
    bool up = (l & m) == 0;
    v0 = up ? __fadd_rn(v0, p0) : __fsub_rn(p0, v0);
    v1 = up ? __fadd_rn(v1, p1) : __fsub_rn(p1, v1);
  }
  {  // m = 64: pair (l, l+64) lane-local
    float A0 = v0, B0 = v1;
    v0 = __fadd_rn(A0, B0);
    v1 = __fsub_rn(A0, B0);
  }
  const float WS = 0.08838834764831843f;  // 128^-0.5
  v0 = __fmul_rn(v0, WS);
  v1 = __fmul_rn(v1, WS);

  float am = fmaxf(fabsf(v0), fabsf(v1));
#pragma unroll
  for (int m = 1; m < 64; m <<= 1) am = fmaxf(am, __shfl_xor(am, m, 64));
  am = fmaxf(am, 1e-4f);
  float ratio = __fdiv_rn(am, 448.0f);
  float l2 = (float)log2((double)ratio);
  float e = ceilf(l2);
  float sf = exp2f(e);
  float inv = __fdiv_rn(1.0f, sf);
  float q0 = __fmul_rn(v0, inv);
  float q1 = __fmul_rn(v1, inv);
  int b0 = __builtin_amdgcn_cvt_pk_fp8_f32(q0, q0, 0, false);
  int b1 = __builtin_amdgcn_cvt_pk_fp8_f32(q1, q1, 0, false);
  out_bytes[l] = (uint8_t)(b0 & 0xff);
  out_bytes[l + 64] = (uint8_t)(b1 & 0xff);
  if (l == 0) *out_scale = sf;
}

// --------------------------------------------------------------- k finalize
// kpart: [8][NT][192] f32, k columns 0..127
__global__ __launch_bounds__(256)
void k_finalize_k(const float* __restrict__ kpart, const float* __restrict__ gamma,
                  const float* __restrict__ beta, const float* __restrict__ cost,
                  const float* __restrict__ sint, uint8_t* __restrict__ kfp8,
                  float* __restrict__ kscale) {
  int l = threadIdx.x & 63;
  int row = blockIdx.x * 4 + (threadIdx.x >> 6);  // t
  float v0 = 0.0f, v1 = 0.0f;
#pragma unroll
  for (int p = 0; p < 8; p++) {
    v0 = __fadd_rn(v0, kpart[(size_t)p * (NT * 192) + row * 192 + l]);
    v1 = __fadd_rn(v1, kpart[(size_t)p * (NT * 192) + row * 192 + l + 64]);
  }
  float s = __fadd_rn(v0, v1);
#pragma unroll
  for (int m = 1; m < 64; m <<= 1) s = __fadd_rn(s, __shfl_xor(s, m, 64));
  float mu = __fmul_rn(s, 0.0078125f);
  float d0 = __fsub_rn(v0, mu), d1 = __fsub_rn(v1, mu);
  float vs = __fadd_rn(__fmul_rn(d0, d0), __fmul_rn(d1, d1));
#pragma unroll
  for (int m = 1; m < 64; m <<= 1) vs = __fadd_rn(vs, __shfl_xor(vs, m, 64));
  float var = __fmul_rn(vs, 0.0078125f);
  float rs = (float)(1.0 / sqrt((double)__fadd_rn(var, 1e-5f)));
  v0 = __fadd_rn(__fmul_rn(__fmul_rn(d0, rs), gamma[l]), beta[l]);
  v1 = __fadd_rn(__fmul_rn(__fmul_rn(d1, rs), gamma[l + 64]), beta[l + 64]);
  rope_fwht_quant(v0, v1, l, row, cost, sint, kfp8 + (size_t)row * ND, kscale + row);
}

// --------------------------------------------------------------- q finalize
__global__ __launch_bounds__(256)
void q_finalize_k(const ushort* __restrict__ qraw, const float* __restrict__ cost,
                  const float* __restrict__ sint, uint8_t* __restrict__ qfp8,
                  float* __restrict__ qscale) {
  int l = threadIdx.x & 63;
  int row = blockIdx.x * 4 + (threadIdx.x >> 6);  // t*64 + h
  int t = row >> 6;
  float v0 = bf2f(qraw[(size_t)row * ND + l]);
  float v1 = bf2f(qraw[(size_t)row * ND + l + 64]);
  rope_fwht_quant(v0, v1, l, t, cost, sint, qfp8 + (size_t)row * ND, qscale + row);
}

// ------------------------------------------------------------------ weights
// wpart = kpart columns 128..191
__global__ __launch_bounds__(256)
void weights_k(const float* __restrict__ kpart, const float* __restrict__ qscale,
               float* __restrict__ weights) {
  int i = blockIdx.x * 256 + threadIdx.x;  // t*64 + h
  int t = i >> 6, h = i & 63;
  float s = 0.0f;
#pragma unroll
  for (int p = 0; p < 8; p++)
    s = __fadd_rn(s, kpart[(size_t)p * (NT * 192) + t * 192 + 128 + h]);
  float w = __fmul_rn(s, 0.125f);
  w = __fmul_rn(w, qscale[i]);
  w = __fmul_rn(w, 0.08838834764831843f);
  weights[i] = w;
}

// ------------------------------------------------------------------- scores
// Block = (4-t tile, 128-s chunk); grid 1152. Q+K staged in LDS via
// global_load_lds with a 16B-granule XOR swizzle (G ^= (row>>1)&7) so that
// ds_read_b64 fragment reads are <=2-way bank-aliased (free). Wave w covers
// s in [w*32, w*32+32) for all 64 heads; h-sum completed in-wave -> scores
// final (kscale factored out, applied in topk; exact for pow2 scales).
__global__ __launch_bounds__(256)
void scores_k(const uint8_t* __restrict__ qfp8, const uint8_t* __restrict__ kfp8,
              const float* __restrict__ weights, float* __restrict__ scores) {
  __shared__ uint8_t q_lds[TTILE * 64 * 128];  // 32KB
  __shared__ uint8_t k_lds[128 * 128];         // 16KB
  __shared__ float w_lds[TTILE * 64];          // 1KB

  int b = blockIdx.x;
  int g = 0;  // t-tile group: tiles [32g,32g+32) have g+1 s-chunks
  while (g < 7 && b >= 16 * (g + 1) * (g + 2)) g++;
  int r = b - 16 * g * (g + 1);
  int a = 32 * g + r / (g + 1);
  int chunk = r % (g + 1);
  int t0 = a * TTILE;
  int s0 = chunk * 128;

  int tid = threadIdx.x;
  int wave = tid >> 6, lane = tid & 63;
  int lg = lane >> 4, ln = lane & 15;

  // ---- stage Q (256 rows x 128B) with inverse-swizzled source, linear dest
  const uint8_t* qbase = qfp8 + (size_t)t0 * 64 * 128;
#pragma unroll
  for (int it = 0; it < 8; it++) {
    int o = it * 256 + wave * 64 + lane;  // 16B-granule index
    int row = o >> 3, G = o & 7;
    int src = row * 128 + ((G ^ ((row >> 1) & 7)) << 4);
    gload_lds16(qbase + src, q_lds + (it * 256 + wave * 64) * 16);
  }
  // ---- stage K (128 rows x 128B)
  const uint8_t* kbase = kfp8 + (size_t)s0 * 128;
#pragma unroll
  for (int it = 0; it < 4; it++) {
    int o = it * 256 + wave * 64 + lane;
    int row = o >> 3, G = o & 7;
    int src = row * 128 + ((G ^ ((row >> 1) & 7)) << 4);
    gload_lds16(kbase + src, k_lds + (it * 256 + wave * 64) * 16);
  }
  w_lds[tid] = weights[t0 * NH + tid];
  __syncthreads();

  // ---- K fragments: loaded once, reused for all 4 t and 4 h-tiles
  long bfr[2][4];
#pragma unroll
  for (int sj = 0; sj < 2; sj++) {
    int srow = wave * 32 + sj * 16 + ln;
    int base = srow * 128;
    int xr = ((srow >> 1) & 7) << 4;
#pragma unroll
    for (int ks = 0; ks < 4; ks++)
      bfr[sj][ks] = *(const long*)(k_lds + base + ((ks * 32 + lg * 8) ^ xr));
  }

  float p[TTILE][2];
#pragma unroll
  for (int tt = 0; tt < TTILE; tt++) p[tt][0] = p[tt][1] = 0.0f;

#pragma unroll
  for (int ht = 0; ht < 4; ht++) {  // head tiles of 16
    long afr[TTILE][4];
#pragma unroll
    for (int tt = 0; tt < TTILE; tt++) {
      int qrow = tt * 64 + ht * 16 + ln;
      int base = qrow * 128;
      int xr = ((qrow >> 1) & 7) << 4;
#pragma unroll
      for (int ks = 0; ks < 4; ks++)
        afr[tt][ks] = *(const long*)(q_lds + base + ((ks * 32 + lg * 8) ^ xr));
    }
#pragma unroll
    for (int tt = 0; tt < TTILE; tt++) {
      float wj[4];
#pragma unroll
      for (int j = 0; j < 4; j++) wj[j] = w_lds[tt * 64 + ht * 16 + lg * 4 + j];
#pragma unroll
      for (int sj = 0; sj < 2; sj++) {
        f32x4 acc = {0.f, 0.f, 0.f, 0.f};
#pragma unroll
        for (int ks = 0; ks < 4; ks++)
          acc = __builtin_amdgcn_mfma_f32_16x16x32_fp8_fp8(afr[tt][ks], bfr[sj][ks],
                                                           acc, 0, 0, 0);
#pragma unroll
        for (int j = 0; j < 4; j++)
          p[tt][sj] = fmaf(wj[j], fmaxf(acc[j], 0.0f), p[tt][sj]);
      }
    }
  }

#pragma unroll
  for (int tt = 0; tt < TTILE; tt++)
#pragma unroll
    for (int sj = 0; sj < 2; sj++) {
      float v = p[tt][sj];
      v += __shfl_xor(v, 16, 64);
      v += __shfl_xor(v, 32, 64);
      if (lg == 0)
        scores[(size_t)(t0 + tt) * NT + s0 + wave * 32 + sj * 16 + ln] = v;
    }
}

// -------------------------------------------------------------------- top-k
__global__ __launch_bounds__(256)
void topk_k(const float* __restrict__ scores, const float* __restrict__ kscale,
            float* __restrict__ outv, float* __restrict__ outi) {
  __shared__ unsigned long long key[1024];
  int t = blockIdx.x, tid = threadIdx.x;
#pragma unroll
  for (int p = 0; p < 4; p++) {
    int s = tid + p * 256;
    float v;
    if (s <= t) {
      v = __fmul_rn(scores[(size_t)t * NT + s], kscale[s]);  // exact pow2 factor
    } else {
      v = -1e30f;
    }
    unsigned u = __float_as_uint(v);
    unsigned ou = (u & 0x80000000u) ? ~u : (u | 0x80000000u);
    key[s] = ((unsigned long long)ou << 32) | (unsigned)(~(unsigned)s);
  }
  for (int k = 2; k <= 1024; k <<= 1) {
    for (int j = k >> 1; j > 0; j >>= 1) {
      __syncthreads();
#pragma unroll
      for (int p = 0; p < 2; p++) {
        int i = tid + p * 256;
        int l = ((i & ~(j - 1)) << 1) | (i & (j - 1));
        int m = l + j;
        bool desc = ((l & k) == 0);
        unsigned long long a = key[l], b = key[m];
        if (desc ? (a < b) : (a > b)) {
          key[l] = b;
          key[m] = a;
        }
      }
    }
  }
  __syncthreads();
#pragma unroll
  for (int p = 0; p < 2; p++) {
    int r = tid + p * 256;
    unsigned long long kk = key[r];
    unsigned ou = (unsigned)(kk >> 32);
    unsigned u = (ou & 0x80000000u) ? (ou ^ 0x80000000u) : ~ou;
    unsigned idx = (~(unsigned)(kk & 0xffffffffu)) & 1023u;
    outv[(size_t)t * NTOPK + r] = __uint_as_float(u);
    outi[(size_t)t * NTOPK + r] = (float)idx;
  }
}

// ------------------------------------------------------------------- launch
extern "C" void kernel_launch(void* const* d_in, const int* in_sizes, int n_in,
                              void* d_out, int out_size, void* d_ws, size_t ws_size,
                              hipStream_t stream) {
  const float* hidden = (const float*)d_in[0];
  const float* q_lora = (const float*)d_in[1];
  const int* positions = (const int*)d_in[2];
  const float* wq_b = (const float*)d_in[3];
  const float* wk = (const float*)d_in[4];
  const float* w_proj = (const float*)d_in[5];
  const float* ln_g = (const float*)d_in[6];
  const float* ln_b = (const float*)d_in[7];
  float* out = (float*)d_out;

  // ---- workspace layout (phase-aliased union region first)
  char* u0 = (char*)d_ws;
  // phase A (hidden-proj): hidden_bf [1024][7168], wkp_t [192][7168]
  ushort* hiddenb = (ushort*)u0;                       // 14,680,064 B
  ushort* wkpt = (ushort*)(u0 + 14680064);             //  2,752,512 B
  // phase B (q): wqb_t [8192][1536], qlora_bf [1024][1536]
  ushort* wqbt = (ushort*)u0;                          // 25,165,824 B
  ushort* qlorab = (ushort*)(u0 + 25165824);           //  3,145,728 B
  // phase C (scores): scores [1024][1024] f32
  float* scores = (float*)u0;                          //  4,194,304 B
  char* p = u0 + 28311552;
  ushort* qrawb = (ushort*)p;  p += 16777216;          // [1024*64][128] bf16
  float* kpart = (float*)p;    p += 6291456;           // [8][1024][192] f32
  float* cost = (float*)p;     p += 131072;
  float* sint = (float*)p;     p += 131072;
  float* kscale = (float*)p;   p += 4096;
  float* qscale = (float*)p;   p += 262144;
  float* weights = (float*)p;  p += 262144;
  uint8_t* kfp8 = (uint8_t*)p; p += 131072;
  uint8_t* qfp8 = (uint8_t*)p; p += 8388608;

  rope_table_k<<<NT, 64, 0, stream>>>(positions, cost, sint);

  // phase A: k + weights projections (combined B = [wk | w_proj], N=192)
  cast_bf16_k<<<NT * NHID / 8 / 256, 256, 0, stream>>>(hidden, hiddenb, NT * NHID / 8);
  tcast_k<<<dim3(2, 112), 256, 0, stream>>>(wk, wkpt, NHID, ND);
  tcast_k<<<dim3(1, 112), 256, 0, stream>>>(w_proj, wkpt + 128 * NHID, NHID, NH);
  gemm_bf16_k<64, false><<<dim3(3, 8, 8), 256, 0, stream>>>(
      hiddenb, wkpt, kpart, NT, 192, NHID, 896);

  // phase B: q projection (overwrites phase-A cast buffers)
  cast_bf16_k<<<NT * NR / 8 / 256, 256, 0, stream>>>(q_lora, qlorab, NT * NR / 8);
  tcast_k<<<dim3(128, 24), 256, 0, stream>>>(wq_b, wqbt, NR, NH * ND);
  gemm_bf16_k<128, true><<<dim3(64, 8, 1), 256, 0, stream>>>(
      qlorab, wqbt, qrawb, NT, NH * ND, NR, NR);

  k_finalize_k<<<NT / 4, 256, 0, stream>>>(kpart, ln_g, ln_b, cost, sint, kfp8, kscale);
  q_finalize_k<<<NT * NH / 4, 256, 0, stream>>>(qrawb, cost, sint, qfp8, qscale);
  weights_k<<<NT * NH / 256, 256, 0, stream>>>(kpart, qscale, weights);

  // phase C: scores (overwrites phase-B cast buffers) + top-k
  scores_k<<<1152, 256, 0, stream>>>(qfp8, kfp8, weights, scores);
  topk_k<<<NT, 256, 0, stream>>>(scores, kscale, out, out + (size_t)NT * NTOPK);
}

// Round 5
// 153.350 us; speedup vs baseline: 3.9463x; 1.0900x over previous
//
#include <hip/hip_runtime.h>
#include <cstdint>
#include <cmath>

// Problem constants (T=1024, HID=7168, R=1536, H=64, D=128, RD=64, TOPK=512)
#define NT 1024
#define NHID 7168
#define NR 1536
#define NH 64
#define ND 128
#define NTOPK 512
#define TTILE 4

typedef float f32x4 __attribute__((ext_vector_type(4)));
typedef short bf16x8 __attribute__((ext_vector_type(8)));
typedef ushort u16x4 __attribute__((ext_vector_type(4)));
typedef ushort u16x8 __attribute__((ext_vector_type(8)));

__device__ __forceinline__ ushort f2bf(float x) {  // RNE f32->bf16
  uint32_t u = __float_as_uint(x);
  u += 0x7fffu + ((u >> 16) & 1u);
  return (ushort)(u >> 16);
}
__device__ __forceinline__ float bf2f(ushort u) {
  return __uint_as_float(((uint32_t)u) << 16);
}
__device__ __forceinline__ void gload_lds16(const void* g, void* l) {
  __builtin_amdgcn_global_load_lds(
      (const __attribute__((address_space(1))) uint32_t*)g,
      (__attribute__((address_space(3))) uint32_t*)l, 16, 0, 0);
}

// ---------------------------------------------------------------- rope table
__global__ void rope_table_k(const int* __restrict__ pos,
                             float* __restrict__ cost, float* __restrict__ sint) {
  int i = threadIdx.x;
  int t = blockIdx.x;
  if (i < 32) {
    double x = (double)(2 * i) / 64.0;
    double p = pow(10000.0, x);
    float p32 = (float)p;
    float invf = __fdiv_rn(1.0f, p32);
    float ang = __fmul_rn((float)pos[t], invf);
    cost[t * 32 + i] = (float)cos((double)ang);
    sint[t * 32 + i] = (float)sin((double)ang);
  }
}

// -------------------------------------------------------------- bf16 casts
__global__ __launch_bounds__(256)
void cast_bf16_k(const float* __restrict__ in, ushort* __restrict__ out, int n8) {
  int i = blockIdx.x * 256 + threadIdx.x;
  if (i >= n8) return;
  const f32x4* p = (const f32x4*)(in + (size_t)i * 8);
  f32x4 a = p[0], b = p[1];
  u16x8 r;
#pragma unroll
  for (int j = 0; j < 4; j++) r[j] = f2bf(a[j]);
#pragma unroll
  for (int j = 0; j < 4; j++) r[4 + j] = f2bf(b[j]);
  *(u16x8*)(out + (size_t)i * 8) = r;
}

// transpose-cast: in [K][N] f32 row-major -> out [N][K] bf16 row-major
__global__ __launch_bounds__(256)
void tcast_k(const float* __restrict__ in, ushort* __restrict__ out, int K, int N) {
  __shared__ ushort t[64][65];
  int tid = threadIdx.x;
  int n0 = blockIdx.x * 64, k0 = blockIdx.y * 64;
  int r = tid >> 4, c = (tid & 15) * 4;
#pragma unroll
  for (int rr = 0; rr < 64; rr += 16) {
    f32x4 v = *(const f32x4*)(in + (size_t)(k0 + rr + r) * N + n0 + c);
#pragma unroll
    for (int j = 0; j < 4; j++) t[rr + r][c + j] = f2bf(v[j]);
  }
  __syncthreads();
#pragma unroll
  for (int rr = 0; rr < 64; rr += 16) {
    int orow = rr + r;  // n-index within tile
    u16x4 w = {t[c + 0][orow], t[c + 1][orow], t[c + 2][orow], t[c + 3][orow]};
    *(u16x4*)(out + (size_t)(n0 + orow) * K + k0 + c) = w;
  }
}

// ------------------------------------------------------------- bf16 GEMM
// BM=128, BK=64, 4 waves (2x2), 4xFN 16x16x32 fragments per wave.
// A [M][K] bf16, Bt [N][K] bf16. Double-buffered LDS (2-phase prefetch);
// 16B-granule XOR swizzle (g ^= (row>>1)&7) applied via inverse-swizzled
// global SOURCE (linear global_load_lds dest) + swizzled ds_read.
// OUTBF: write bf16 (z ignored), else f32 parts C[z*M*N + m*N + n].
template <int BN, bool OUTBF>
__global__ __launch_bounds__(256)
void gemm_bf16_k(const ushort* __restrict__ A, const ushort* __restrict__ Bt,
                 void* __restrict__ Cv, int M, int N, int K, int kchunk) {
  constexpr int FN = BN / 32;
  __shared__ ushort As[2 * 128 * 64];
  __shared__ ushort Bs[2 * BN * 64];
  int tid = threadIdx.x;
  int wave = tid >> 6, lane = tid & 63;
  int ln = lane & 15, lg = lane >> 4;
  int n0 = blockIdx.x * BN, m0 = blockIdx.y * 128;
  int k0 = blockIdx.z * kchunk;
  int wm = (wave >> 1) * 64, wn = (wave & 1) * (BN / 2);

  f32x4 acc[4][FN];
#pragma unroll
  for (int m = 0; m < 4; m++)
#pragma unroll
    for (int n = 0; n < FN; n++) acc[m][n] = {0.f, 0.f, 0.f, 0.f};

  // stage one 64-wide K-tile into buffer `buf` (linear dest, swizzled src)
  auto stage = [&](int buf, int kk0) {
#pragma unroll
    for (int c = 0; c < 4; c++) {  // A: 128 rows x 128B
      int o = c * 256 + wave * 64 + lane;  // 16B-granule id
      int row = o >> 3, g = o & 7;
      int gs = g ^ ((row >> 1) & 7);
      gload_lds16(A + (size_t)(m0 + row) * K + kk0 + gs * 8,
                  (char*)As + buf * 16384 + (c * 256 + wave * 64) * 16);
    }
#pragma unroll
    for (int c = 0; c < BN / 32; c++) {  // B: BN rows x 128B
      int o = c * 256 + wave * 64 + lane;
      int row = o >> 3, g = o & 7;
      int gs = g ^ ((row >> 1) & 7);
      gload_lds16(Bt + (size_t)(n0 + row) * K + kk0 + gs * 8,
                  (char*)Bs + buf * (BN * 128) + (c * 256 + wave * 64) * 16);
    }
  };

  int ntile = kchunk / 64;
  stage(0, k0);
  __syncthreads();
  int cur = 0;
  for (int t = 0; t < ntile; t++) {
    if (t + 1 < ntile) stage(cur ^ 1, k0 + (t + 1) * 64);
    const ushort* ap = As + cur * (128 * 64);
    const ushort* bp = Bs + cur * (BN * 64);
#pragma unroll
    for (int kk = 0; kk < 2; kk++) {
      bf16x8 af[4], bfr[FN];
#pragma unroll
      for (int m = 0; m < 4; m++) {
        int row = wm + m * 16 + ln;
        int gsw = (kk * 4 + lg) ^ ((row >> 1) & 7);
        af[m] = *(const bf16x8*)(ap + row * 64 + gsw * 8);
      }
#pragma unroll
      for (int n = 0; n < FN; n++) {
        int row = wn + n * 16 + ln;
        int gsw = (kk * 4 + lg) ^ ((row >> 1) & 7);
        bfr[n] = *(const bf16x8*)(bp + row * 64 + gsw * 8);
      }
#pragma unroll
      for (int m = 0; m < 4; m++)
#pragma unroll
        for (int n = 0; n < FN; n++)
          acc[m][n] = __builtin_amdgcn_mfma_f32_16x16x32_bf16(af[m], bfr[n],
                                                              acc[m][n], 0, 0, 0);
    }
    __syncthreads();  // drains prefetch (vmcnt) + read completion; flip
    cur ^= 1;
  }

  if constexpr (OUTBF) {
    ushort* Cb = (ushort*)Cv;
#pragma unroll
    for (int m = 0; m < 4; m++)
#pragma unroll
      for (int n = 0; n < FN; n++)
#pragma unroll
        for (int j = 0; j < 4; j++) {
          int row = m0 + wm + m * 16 + lg * 4 + j;
          int col = n0 + wn + n * 16 + ln;
          Cb[(size_t)row * N + col] = f2bf(acc[m][n][j]);
        }
  } else {
    float* C = (float*)Cv + (size_t)blockIdx.z * M * N;
#pragma unroll
    for (int m = 0; m < 4; m++)
#pragma unroll
      for (int n = 0; n < FN; n++)
#pragma unroll
        for (int j = 0; j < 4; j++) {
          int row = m0 + wm + m * 16 + lg * 4 + j;
          int col = n0 + wn + n * 16 + ln;
          C[(size_t)row * N + col] = acc[m][n][j];
        }
  }
}

// ---------------------------------------------------------- rope+fwht+quant
// One wave per 128-elem row: lane l owns elements l and l+64.
__device__ __forceinline__ void rope_fwht_quant(
    float v0, float v1, int l, int pos_t,
    const float* __restrict__ cost, const float* __restrict__ sint,
    uint8_t* __restrict__ out_bytes, float* __restrict__ out_scale) {
  float a = __shfl(v0, (2 * l) & 63, 64);      // x[2i]
  float b = __shfl(v0, (2 * l + 1) & 63, 64);  // x[2i+1]
  int fi = l & 31;
  float c = cost[pos_t * 32 + fi];
  float sn = sint[pos_t * 32 + fi];
  float r;
  if (l < 32)
    r = __fsub_rn(__fmul_rn(a, c), __fmul_rn(b, sn));
  else
    r = __fadd_rn(__fmul_rn(b, c), __fmul_rn(a, sn));
  v0 = r;  // elements 64..127 untouched by rope

#pragma unroll
  for (int m = 1; m < 64; m <<= 1) {  // FWHT Sylvester order
    float p0 = __shfl_xor(v0, m, 64);
    float p1 = __shfl_xor(v1, m, 64);
    bool up = (l & m) == 0;
    v0 = up ? __fadd_rn(v0, p0) : __fsub_rn(p0, v0);
    v1 = up ? __fadd_rn(v1, p1) : __fsub_rn(p1, v1);
  }
  {  // m = 64: pair (l, l+64) lane-local
    float A0 = v0, B0 = v1;
    v0 = __fadd_rn(A0, B0);
    v1 = __fsub_rn(A0, B0);
  }
  const float WS = 0.08838834764831843f;  // 128^-0.5
  v0 = __fmul_rn(v0, WS);
  v1 = __fmul_rn(v1, WS);

  float am = fmaxf(fabsf(v0), fabsf(v1));
#pragma unroll
  for (int m = 1; m < 64; m <<= 1) am = fmaxf(am, __shfl_xor(am, m, 64));
  am = fmaxf(am, 1e-4f);
  float ratio = __fdiv_rn(am, 448.0f);
  float l2 = (float)log2((double)ratio);
  float e = ceilf(l2);
  float sf = exp2f(e);
  float inv = __fdiv_rn(1.0f, sf);
  float q0 = __fmul_rn(v0, inv);
  float q1 = __fmul_rn(v1, inv);
  int b0 = __builtin_amdgcn_cvt_pk_fp8_f32(q0, q0, 0, false);
  int b1 = __builtin_amdgcn_cvt_pk_fp8_f32(q1, q1, 0, false);
  out_bytes[l] = (uint8_t)(b0 & 0xff);
  out_bytes[l + 64] = (uint8_t)(b1 & 0xff);
  if (l == 0) *out_scale = sf;
}

// --------------------------------------------------------------- k finalize
// kpart: [8][NT][192] f32, k columns 0..127
__global__ __launch_bounds__(256)
void k_finalize_k(const float* __restrict__ kpart, const float* __restrict__ gamma,
                  const float* __restrict__ beta, const float* __restrict__ cost,
                  const float* __restrict__ sint, uint8_t* __restrict__ kfp8,
                  float* __restrict__ kscale) {
  int l = threadIdx.x & 63;
  int row = blockIdx.x * 4 + (threadIdx.x >> 6);  // t
  float v0 = 0.0f, v1 = 0.0f;
#pragma unroll
  for (int p = 0; p < 8; p++) {
    v0 = __fadd_rn(v0, kpart[(size_t)p * (NT * 192) + row * 192 + l]);
    v1 = __fadd_rn(v1, kpart[(size_t)p * (NT * 192) + row * 192 + l + 64]);
  }
  float s = __fadd_rn(v0, v1);
#pragma unroll
  for (int m = 1; m < 64; m <<= 1) s = __fadd_rn(s, __shfl_xor(s, m, 64));
  float mu = __fmul_rn(s, 0.0078125f);
  float d0 = __fsub_rn(v0, mu), d1 = __fsub_rn(v1, mu);
  float vs = __fadd_rn(__fmul_rn(d0, d0), __fmul_rn(d1, d1));
#pragma unroll
  for (int m = 1; m < 64; m <<= 1) vs = __fadd_rn(vs, __shfl_xor(vs, m, 64));
  float var = __fmul_rn(vs, 0.0078125f);
  float rs = (float)(1.0 / sqrt((double)__fadd_rn(var, 1e-5f)));
  v0 = __fadd_rn(__fmul_rn(__fmul_rn(d0, rs), gamma[l]), beta[l]);
  v1 = __fadd_rn(__fmul_rn(__fmul_rn(d1, rs), gamma[l + 64]), beta[l + 64]);
  rope_fwht_quant(v0, v1, l, row, cost, sint, kfp8 + (size_t)row * ND, kscale + row);
}

// --------------------------------------------------------------- q finalize
__global__ __launch_bounds__(256)
void q_finalize_k(const ushort* __restrict__ qraw, const float* __restrict__ cost,
                  const float* __restrict__ sint, uint8_t* __restrict__ qfp8,
                  float* __restrict__ qscale) {
  int l = threadIdx.x & 63;
  int row = blockIdx.x * 4 + (threadIdx.x >> 6);  // t*64 + h
  int t = row >> 6;
  float v0 = bf2f(qraw[(size_t)row * ND + l]);
  float v1 = bf2f(qraw[(size_t)row * ND + l + 64]);
  rope_fwht_quant(v0, v1, l, t, cost, sint, qfp8 + (size_t)row * ND, qscale + row);
}

// ------------------------------------------------------------------ weights
// wpart = kpart columns 128..191
__global__ __launch_bounds__(256)
void weights_k(const float* __restrict__ kpart, const float* __restrict__ qscale,
               float* __restrict__ weights) {
  int i = blockIdx.x * 256 + threadIdx.x;  // t*64 + h
  int t = i >> 6, h = i & 63;
  float s = 0.0f;
#pragma unroll
  for (int p = 0; p < 8; p++)
    s = __fadd_rn(s, kpart[(size_t)p * (NT * 192) + t * 192 + 128 + h]);
  float w = __fmul_rn(s, 0.125f);
  w = __fmul_rn(w, qscale[i]);
  w = __fmul_rn(w, 0.08838834764831843f);
  weights[i] = w;
}

// ------------------------------------------------------------------- scores
// Block = (4-t tile, 128-s chunk); grid 1152. Q+K staged in LDS via
// global_load_lds with a 16B-granule XOR swizzle (G ^= (row>>1)&7) so that
// ds_read_b64 fragment reads are <=2-way bank-aliased (free). Wave w covers
// s in [w*32, w*32+32) for all 64 heads; h-sum completed in-wave -> scores
// final (kscale factored out, applied in topk; exact for pow2 scales).
__global__ __launch_bounds__(256)
void scores_k(const uint8_t* __restrict__ qfp8, const uint8_t* __restrict__ kfp8,
              const float* __restrict__ weights, float* __restrict__ scores) {
  __shared__ uint8_t q_lds[TTILE * 64 * 128];  // 32KB
  __shared__ uint8_t k_lds[128 * 128];         // 16KB
  __shared__ float w_lds[TTILE * 64];          // 1KB

  int b = blockIdx.x;
  int g = 0;  // t-tile group: tiles [32g,32g+32) have g+1 s-chunks
  while (g < 7 && b >= 16 * (g + 1) * (g + 2)) g++;
  int r = b - 16 * g * (g + 1);
  int a = 32 * g + r / (g + 1);
  int chunk = r % (g + 1);
  int t0 = a * TTILE;
  int s0 = chunk * 128;

  int tid = threadIdx.x;
  int wave = tid >> 6, lane = tid & 63;
  int lg = lane >> 4, ln = lane & 15;

  // ---- stage Q (256 rows x 128B) with inverse-swizzled source, linear dest
  const uint8_t* qbase = qfp8 + (size_t)t0 * 64 * 128;
#pragma unroll
  for (int it = 0; it < 8; it++) {
    int o = it * 256 + wave * 64 + lane;  // 16B-granule index
    int row = o >> 3, G = o & 7;
    int src = row * 128 + ((G ^ ((row >> 1) & 7)) << 4);
    gload_lds16(qbase + src, q_lds + (it * 256 + wave * 64) * 16);
  }
  // ---- stage K (128 rows x 128B)
  const uint8_t* kbase = kfp8 + (size_t)s0 * 128;
#pragma unroll
  for (int it = 0; it < 4; it++) {
    int o = it * 256 + wave * 64 + lane;
    int row = o >> 3, G = o & 7;
    int src = row * 128 + ((G ^ ((row >> 1) & 7)) << 4);
    gload_lds16(kbase + src, k_lds + (it * 256 + wave * 64) * 16);
  }
  w_lds[tid] = weights[t0 * NH + tid];
  __syncthreads();

  // ---- K fragments: loaded once, reused for all 4 t and 4 h-tiles
  long bfr[2][4];
#pragma unroll
  for (int sj = 0; sj < 2; sj++) {
    int srow = wave * 32 + sj * 16 + ln;
    int base = srow * 128;
    int xr = ((srow >> 1) & 7) << 4;
#pragma unroll
    for (int ks = 0; ks < 4; ks++)
      bfr[sj][ks] = *(const long*)(k_lds + base + ((ks * 32 + lg * 8) ^ xr));
  }

  float p[TTILE][2];
#pragma unroll
  for (int tt = 0; tt < TTILE; tt++) p[tt][0] = p[tt][1] = 0.0f;

#pragma unroll
  for (int ht = 0; ht < 4; ht++) {  // head tiles of 16
    long afr[TTILE][4];
#pragma unroll
    for (int tt = 0; tt < TTILE; tt++) {
      int qrow = tt * 64 + ht * 16 + ln;
      int base = qrow * 128;
      int xr = ((qrow >> 1) & 7) << 4;
#pragma unroll
      for (int ks = 0; ks < 4; ks++)
        afr[tt][ks] = *(const long*)(q_lds + base + ((ks * 32 + lg * 8) ^ xr));
    }
#pragma unroll
    for (int tt = 0; tt < TTILE; tt++) {
      float wj[4];
#pragma unroll
      for (int j = 0; j < 4; j++) wj[j] = w_lds[tt * 64 + ht * 16 + lg * 4 + j];
#pragma unroll
      for (int sj = 0; sj < 2; sj++) {
        f32x4 acc = {0.f, 0.f, 0.f, 0.f};
#pragma unroll
        for (int ks = 0; ks < 4; ks++)
          acc = __builtin_amdgcn_mfma_f32_16x16x32_fp8_fp8(afr[tt][ks], bfr[sj][ks],
                                                           acc, 0, 0, 0);
#pragma unroll
        for (int j = 0; j < 4; j++)
          p[tt][sj] = fmaf(wj[j], fmaxf(acc[j], 0.0f), p[tt][sj]);
      }
    }
  }

#pragma unroll
  for (int tt = 0; tt < TTILE; tt++)
#pragma unroll
    for (int sj = 0; sj < 2; sj++) {
      float v = p[tt][sj];
      v += __shfl_xor(v, 16, 64);
      v += __shfl_xor(v, 32, 64);
      if (lg == 0)
        scores[(size_t)(t0 + tt) * NT + s0 + wave * 32 + sj * 16 + ln] = v;
    }
}

// -------------------------------------------------------------------- top-k
__global__ __launch_bounds__(256)
void topk_k(const float* __restrict__ scores, const float* __restrict__ kscale,
            float* __restrict__ outv, float* __restrict__ outi) {
  __shared__ unsigned long long key[1024];
  int t = blockIdx.x, tid = threadIdx.x;
#pragma unroll
  for (int p = 0; p < 4; p++) {
    int s = tid + p * 256;
    float v;
    if (s <= t) {
      v = __fmul_rn(scores[(size_t)t * NT + s], kscale[s]);  // exact pow2 factor
    } else {
      v = -1e30f;
    }
    unsigned u = __float_as_uint(v);
    unsigned ou = (u & 0x80000000u) ? ~u : (u | 0x80000000u);
    key[s] = ((unsigned long long)ou << 32) | (unsigned)(~(unsigned)s);
  }
  for (int k = 2; k <= 1024; k <<= 1) {
    for (int j = k >> 1; j > 0; j >>= 1) {
      __syncthreads();
#pragma unroll
      for (int p = 0; p < 2; p++) {
        int i = tid + p * 256;
        int l = ((i & ~(j - 1)) << 1) | (i & (j - 1));
        int m = l + j;
        bool desc = ((l & k) == 0);
        unsigned long long a = key[l], b = key[m];
        if (desc ? (a < b) : (a > b)) {
          key[l] = b;
          key[m] = a;
        }
      }
    }
  }
  __syncthreads();
#pragma unroll
  for (int p = 0; p < 2; p++) {
    int r = tid + p * 256;
    unsigned long long kk = key[r];
    unsigned ou = (unsigned)(kk >> 32);
    unsigned u = (ou & 0x80000000u) ? (ou ^ 0x80000000u) : ~ou;
    unsigned idx = (~(unsigned)(kk & 0xffffffffu)) & 1023u;
    outv[(size_t)t * NTOPK + r] = __uint_as_float(u);
    outi[(size_t)t * NTOPK + r] = (float)idx;
  }
}

// ------------------------------------------------------------------- launch
extern "C" void kernel_launch(void* const* d_in, const int* in_sizes, int n_in,
                              void* d_out, int out_size, void* d_ws, size_t ws_size,
                              hipStream_t stream) {
  const float* hidden = (const float*)d_in[0];
  const float* q_lora = (const float*)d_in[1];
  const int* positions = (const int*)d_in[2];
  const float* wq_b = (const float*)d_in[3];
  const float* wk = (const float*)d_in[4];
  const float* w_proj = (const float*)d_in[5];
  const float* ln_g = (const float*)d_in[6];
  const float* ln_b = (const float*)d_in[7];
  float* out = (float*)d_out;

  // ---- workspace layout (phase-aliased union region first)
  char* u0 = (char*)d_ws;
  // phase A (hidden-proj): hidden_bf [1024][7168], wkp_t [192][7168]
  ushort* hiddenb = (ushort*)u0;                       // 14,680,064 B
  ushort* wkpt = (ushort*)(u0 + 14680064);             //  2,752,512 B
  // phase B (q): wqb_t [8192][1536], qlora_bf [1024][1536]
  ushort* wqbt = (ushort*)u0;                          // 25,165,824 B
  ushort* qlorab = (ushort*)(u0 + 25165824);           //  3,145,728 B
  // phase C (scores): scores [1024][1024] f32
  float* scores = (float*)u0;                          //  4,194,304 B
  char* p = u0 + 28311552;
  ushort* qrawb = (ushort*)p;  p += 16777216;          // [1024*64][128] bf16
  float* kpart = (float*)p;    p += 6291456;           // [8][1024][192] f32
  float* cost = (float*)p;     p += 131072;
  float* sint = (float*)p;     p += 131072;
  float* kscale = (float*)p;   p += 4096;
  float* qscale = (float*)p;   p += 262144;
  float* weights = (float*)p;  p += 262144;
  uint8_t* kfp8 = (uint8_t*)p; p += 131072;
  uint8_t* qfp8 = (uint8_t*)p; p += 8388608;

  rope_table_k<<<NT, 64, 0, stream>>>(positions, cost, sint);

  // phase A: k + weights projections (combined B = [wk | w_proj], N=192)
  cast_bf16_k<<<NT * NHID / 8 / 256, 256, 0, stream>>>(hidden, hiddenb, NT * NHID / 8);
  tcast_k<<<dim3(2, 112), 256, 0, stream>>>(wk, wkpt, NHID, ND);
  tcast_k<<<dim3(1, 112), 256, 0, stream>>>(w_proj, wkpt + 128 * NHID, NHID, NH);
  gemm_bf16_k<64, false><<<dim3(3, 8, 8), 256, 0, stream>>>(
      hiddenb, wkpt, kpart, NT, 192, NHID, 896);

  // phase B: q projection (overwrites phase-A cast buffers)
  cast_bf16_k<<<NT * NR / 8 / 256, 256, 0, stream>>>(q_lora, qlorab, NT * NR / 8);
  tcast_k<<<dim3(128, 24), 256, 0, stream>>>(wq_b, wqbt, NR, NH * ND);
  gemm_bf16_k<128, true><<<dim3(64, 8, 1), 256, 0, stream>>>(
      qlorab, wqbt, qrawb, NT, NH * ND, NR, NR);

  k_finalize_k<<<NT / 4, 256, 0, stream>>>(kpart, ln_g, ln_b, cost, sint, kfp8, kscale);
  q_finalize_k<<<NT * NH / 4, 256, 0, stream>>>(qrawb, cost, sint, qfp8, qscale);
  weights_k<<<NT * NH / 256, 256, 0, stream>>>(kpart, qscale, weights);

  // phase C: scores (overwrites phase-B cast buffers) + top-k
  scores_k<<<1152, 256, 0, stream>>>(qfp8, kfp8, weights, scores);
  topk_k<<<NT, 256, 0, stream>>>(scores, kscale, out, out + (size_t)NT * NTOPK);
}

// Round 6
// 152.584 us; speedup vs baseline: 3.9661x; 1.0050x over previous
//
#include <hip/hip_runtime.h>
#include <cstdint>
#include <cmath>

// Problem constants (T=1024, HID=7168, R=1536, H=64, D=128, RD=64, TOPK=512)
#define NT 1024
#define NHID 7168
#define NR 1536
#define NH 64
#define ND 128
#define NTOPK 512
#define TTILE 4
#define KSPLIT 16

typedef float f32x4 __attribute__((ext_vector_type(4)));
typedef short bf16x8 __attribute__((ext_vector_type(8)));
typedef ushort u16x4 __attribute__((ext_vector_type(4)));
typedef ushort u16x8 __attribute__((ext_vector_type(8)));

__device__ __forceinline__ ushort f2bf(float x) {  // RNE f32->bf16
  uint32_t u = __float_as_uint(x);
  u += 0x7fffu + ((u >> 16) & 1u);
  return (ushort)(u >> 16);
}
__device__ __forceinline__ float bf2f(ushort u) {
  return __uint_as_float(((uint32_t)u) << 16);
}
__device__ __forceinline__ void gload_lds16(const void* g, void* l) {
  __builtin_amdgcn_global_load_lds(
      (const __attribute__((address_space(1))) uint32_t*)g,
      (__attribute__((address_space(3))) uint32_t*)l, 16, 0, 0);
}

// ---------------------------------------------------------------- rope table
__global__ void rope_table_k(const int* __restrict__ pos,
                             float* __restrict__ cost, float* __restrict__ sint) {
  int i = threadIdx.x;
  int t = blockIdx.x;
  if (i < 32) {
    double x = (double)(2 * i) / 64.0;
    double p = pow(10000.0, x);
    float p32 = (float)p;
    float invf = __fdiv_rn(1.0f, p32);
    float ang = __fmul_rn((float)pos[t], invf);
    cost[t * 32 + i] = (float)cos((double)ang);
    sint[t * 32 + i] = (float)sin((double)ang);
  }
}

// -------------------------------------------------------------- bf16 casts
__global__ __launch_bounds__(256)
void cast_bf16_k(const float* __restrict__ in, ushort* __restrict__ out, int n8) {
  int i = blockIdx.x * 256 + threadIdx.x;
  if (i >= n8) return;
  const f32x4* p = (const f32x4*)(in + (size_t)i * 8);
  f32x4 a = p[0], b = p[1];
  u16x8 r;
#pragma unroll
  for (int j = 0; j < 4; j++) r[j] = f2bf(a[j]);
#pragma unroll
  for (int j = 0; j < 4; j++) r[4 + j] = f2bf(b[j]);
  *(u16x8*)(out + (size_t)i * 8) = r;
}

// transpose-cast: in [K][N] f32 row-major -> out [N][K] bf16 row-major
__global__ __launch_bounds__(256)
void tcast_k(const float* __restrict__ in, ushort* __restrict__ out, int K, int N) {
  __shared__ ushort t[64][65];
  int tid = threadIdx.x;
  int n0 = blockIdx.x * 64, k0 = blockIdx.y * 64;
  int r = tid >> 4, c = (tid & 15) * 4;
#pragma unroll
  for (int rr = 0; rr < 64; rr += 16) {
    f32x4 v = *(const f32x4*)(in + (size_t)(k0 + rr + r) * N + n0 + c);
#pragma unroll
    for (int j = 0; j < 4; j++) t[rr + r][c + j] = f2bf(v[j]);
  }
  __syncthreads();
#pragma unroll
  for (int rr = 0; rr < 64; rr += 16) {
    int orow = rr + r;  // n-index within tile
    u16x4 w = {t[c + 0][orow], t[c + 1][orow], t[c + 2][orow], t[c + 3][orow]};
    *(u16x4*)(out + (size_t)(n0 + orow) * K + k0 + c) = w;
  }
}

// ---------------------------------------------------------- rope+fwht+quant
// One wave per 128-elem row: lane l owns elements l and l+64.
__device__ __forceinline__ void rope_fwht_quant(
    float v0, float v1, int l, int pos_t,
    const float* __restrict__ cost, const float* __restrict__ sint,
    uint8_t* __restrict__ out_bytes, float* __restrict__ out_scale) {
  float a = __shfl(v0, (2 * l) & 63, 64);      // x[2i]
  float b = __shfl(v0, (2 * l + 1) & 63, 64);  // x[2i+1]
  int fi = l & 31;
  float c = cost[pos_t * 32 + fi];
  float sn = sint[pos_t * 32 + fi];
  float r;
  if (l < 32)
    r = __fsub_rn(__fmul_rn(a, c), __fmul_rn(b, sn));
  else
    r = __fadd_rn(__fmul_rn(b, c), __fmul_rn(a, sn));
  v0 = r;  // elements 64..127 untouched by rope

#pragma unroll
  for (int m = 1; m < 64; m <<= 1) {  // FWHT Sylvester order
    float p0 = __shfl_xor(v0, m, 64);
    float p1 = __shfl_xor(v1, m, 64);
    bool up = (l & m) == 0;
    v0 = up ? __fadd_rn(v0, p0) : __fsub_rn(p0, v0);
    v1 = up ? __fadd_rn(v1, p1) : __fsub_rn(p1, v1);
  }
  {  // m = 64: pair (l, l+64) lane-local
    float A0 = v0, B0 = v1;
    v0 = __fadd_rn(A0, B0);
    v1 = __fsub_rn(A0, B0);
  }
  const float WS = 0.08838834764831843f;  // 128^-0.5
  v0 = __fmul_rn(v0, WS);
  v1 = __fmul_rn(v1, WS);

  float am = fmaxf(fabsf(v0), fabsf(v1));
#pragma unroll
  for (int m = 1; m < 64; m <<= 1) am = fmaxf(am, __shfl_xor(am, m, 64));
  am = fmaxf(am, 1e-4f);
  float ratio = __fdiv_rn(am, 448.0f);
  // exact ceil(log2(ratio)) via mantissa test (UE8M0)
  uint32_t rb = __float_as_uint(ratio);
  int e = (int)((rb + 0x7fffffu) >> 23) - 127;
  float sf = __uint_as_float((uint32_t)(e + 127) << 23);
  float inv = __uint_as_float((uint32_t)(127 - e) << 23);
  float q0 = __fmul_rn(v0, inv);
  float q1 = __fmul_rn(v1, inv);
  int b0 = __builtin_amdgcn_cvt_pk_fp8_f32(q0, q0, 0, false);
  int b1 = __builtin_amdgcn_cvt_pk_fp8_f32(q1, q1, 0, false);
  out_bytes[l] = (uint8_t)(b0 & 0xff);
  out_bytes[l + 64] = (uint8_t)(b1 & 0xff);
  if (l == 0) *out_scale = sf;
}

// ------------------------------------------------------------- bf16 GEMM
// BM=128, BK=64, 4 waves (2x2). Counted-vmcnt double-buffered pipeline:
// stage(t+1) -> vmcnt(NLD) [gates stage(t), issued a full iter ago] ->
// s_barrier -> ds_read+MFMA -> s_barrier. Never drains vmcnt(0) mid-loop.
// 16B-granule XOR swizzle (g ^= (row>>1)&7): inverse-swizzled global src,
// linear LDS dest, swizzled ds_read (rule #21).
// FUSEQ: BN=128 block = (128 t-rows) x (one head's D=128); epilogue runs
// rope+FWHT+fp8 quant in-kernel (reuses As as 128x128 bf16 tile).
template <int BN, bool FUSEQ>
__global__ __launch_bounds__(256)
void gemm_bf16_k(const ushort* __restrict__ A, const ushort* __restrict__ Bt,
                 void* __restrict__ Cv, int M, int N, int K, int kchunk,
                 const float* __restrict__ cost, const float* __restrict__ sint,
                 uint8_t* __restrict__ qfp8, float* __restrict__ qscale) {
  constexpr int FN = BN / 32;
  __shared__ ushort As[2 * 128 * 64];
  __shared__ ushort Bs[2 * BN * 64];
  int tid = threadIdx.x;
  int wave = tid >> 6, lane = tid & 63;
  int ln = lane & 15, lg = lane >> 4;
  int n0 = blockIdx.x * BN, m0 = blockIdx.y * 128;
  int k0 = blockIdx.z * kchunk;
  int wm = (wave >> 1) * 64, wn = (wave & 1) * (BN / 2);

  f32x4 acc[4][FN];
#pragma unroll
  for (int m = 0; m < 4; m++)
#pragma unroll
    for (int n = 0; n < FN; n++) acc[m][n] = {0.f, 0.f, 0.f, 0.f};

  auto stage = [&](int buf, int kk0) {
#pragma unroll
    for (int c = 0; c < 4; c++) {  // A: 128 rows x 128B
      int o = c * 256 + wave * 64 + lane;  // 16B-granule id
      int row = o >> 3, g = o & 7;
      int gs = g ^ ((row >> 1) & 7);
      gload_lds16(A + (size_t)(m0 + row) * K + kk0 + gs * 8,
                  (char*)As + buf * 16384 + (c * 256 + wave * 64) * 16);
    }
#pragma unroll
    for (int c = 0; c < BN / 32; c++) {  // B: BN rows x 128B
      int o = c * 256 + wave * 64 + lane;
      int row = o >> 3, g = o & 7;
      int gs = g ^ ((row >> 1) & 7);
      gload_lds16(Bt + (size_t)(n0 + row) * K + kk0 + gs * 8,
                  (char*)Bs + buf * (BN * 128) + (c * 256 + wave * 64) * 16);
    }
  };

  int ntile = kchunk / 64;
  stage(0, k0);
  int cur = 0;
  for (int t = 0; t < ntile; t++) {
    if (t + 1 < ntile) {
      stage(cur ^ 1, k0 + (t + 1) * 64);
      if constexpr (BN == 128)
        asm volatile("s_waitcnt vmcnt(8)" ::: "memory");
      else
        asm volatile("s_waitcnt vmcnt(6)" ::: "memory");
    } else {
      asm volatile("s_waitcnt vmcnt(0)" ::: "memory");
    }
    __builtin_amdgcn_s_barrier();
    __builtin_amdgcn_sched_barrier(0);
    const ushort* ap = As + cur * (128 * 64);
    const ushort* bp = Bs + cur * (BN * 64);
#pragma unroll
    for (int kk = 0; kk < 2; kk++) {
      bf16x8 af[4], bfr[FN];
#pragma unroll
      for (int m = 0; m < 4; m++) {
        int row = wm + m * 16 + ln;
        int gsw = (kk * 4 + lg) ^ ((row >> 1) & 7);
        af[m] = *(const bf16x8*)(ap + row * 64 + gsw * 8);
      }
#pragma unroll
      for (int n = 0; n < FN; n++) {
        int row = wn + n * 16 + ln;
        int gsw = (kk * 4 + lg) ^ ((row >> 1) & 7);
        bfr[n] = *(const bf16x8*)(bp + row * 64 + gsw * 8);
      }
#pragma unroll
      for (int m = 0; m < 4; m++)
#pragma unroll
        for (int n = 0; n < FN; n++)
          acc[m][n] = __builtin_amdgcn_mfma_f32_16x16x32_bf16(af[m], bfr[n],
                                                              acc[m][n], 0, 0, 0);
    }
    __builtin_amdgcn_sched_barrier(0);
    __builtin_amdgcn_s_barrier();
    cur ^= 1;
  }

  if constexpr (FUSEQ) {
    // acc -> bf16 tile in As (exactly 128x128 ushorts = 32KB)
#pragma unroll
    for (int m = 0; m < 4; m++)
#pragma unroll
      for (int n = 0; n < FN; n++)
#pragma unroll
        for (int j = 0; j < 4; j++) {
          int row = wm + m * 16 + lg * 4 + j;
          int col = wn + n * 16 + ln;
          As[row * 128 + col] = f2bf(acc[m][n][j]);
        }
    __syncthreads();
    int h = blockIdx.x;  // BN=128 and N=8192: one head per block column
    for (int r = 0; r < 32; r++) {
      int row = wave * 32 + r;
      int tq = m0 + row;
      float v0 = bf2f(As[row * 128 + lane]);
      float v1 = bf2f(As[row * 128 + 64 + lane]);
      rope_fwht_quant(v0, v1, lane, tq, cost, sint,
                      qfp8 + ((size_t)tq * NH + h) * ND,
                      qscale + (size_t)tq * NH + h);
    }
  } else {
    float* C = (float*)Cv + (size_t)blockIdx.z * M * N;
#pragma unroll
    for (int m = 0; m < 4; m++)
#pragma unroll
      for (int n = 0; n < FN; n++)
#pragma unroll
        for (int j = 0; j < 4; j++) {
          int row = m0 + wm + m * 16 + lg * 4 + j;
          int col = n0 + wn + n * 16 + ln;
          C[(size_t)row * N + col] = acc[m][n][j];
        }
  }
}

// --------------------------------------------------------------- k finalize
// kpart: [KSPLIT][NT][192] f32, k columns 0..127
__global__ __launch_bounds__(256)
void k_finalize_k(const float* __restrict__ kpart, const float* __restrict__ gamma,
                  const float* __restrict__ beta, const float* __restrict__ cost,
                  const float* __restrict__ sint, uint8_t* __restrict__ kfp8,
                  float* __restrict__ kscale) {
  int l = threadIdx.x & 63;
  int row = blockIdx.x * 4 + (threadIdx.x >> 6);  // t
  float v0 = 0.0f, v1 = 0.0f;
#pragma unroll
  for (int p = 0; p < KSPLIT; p++) {
    v0 = __fadd_rn(v0, kpart[(size_t)p * (NT * 192) + row * 192 + l]);
    v1 = __fadd_rn(v1, kpart[(size_t)p * (NT * 192) + row * 192 + l + 64]);
  }
  float s = __fadd_rn(v0, v1);
#pragma unroll
  for (int m = 1; m < 64; m <<= 1) s = __fadd_rn(s, __shfl_xor(s, m, 64));
  float mu = __fmul_rn(s, 0.0078125f);
  float d0 = __fsub_rn(v0, mu), d1 = __fsub_rn(v1, mu);
  float vs = __fadd_rn(__fmul_rn(d0, d0), __fmul_rn(d1, d1));
#pragma unroll
  for (int m = 1; m < 64; m <<= 1) vs = __fadd_rn(vs, __shfl_xor(vs, m, 64));
  float var = __fmul_rn(vs, 0.0078125f);
  float rs = (float)(1.0 / sqrt((double)__fadd_rn(var, 1e-5f)));
  v0 = __fadd_rn(__fmul_rn(__fmul_rn(d0, rs), gamma[l]), beta[l]);
  v1 = __fadd_rn(__fmul_rn(__fmul_rn(d1, rs), gamma[l + 64]), beta[l + 64]);
  rope_fwht_quant(v0, v1, l, row, cost, sint, kfp8 + (size_t)row * ND, kscale + row);
}

// ------------------------------------------------------------------ weights
// wpart = kpart columns 128..191
__global__ __launch_bounds__(256)
void weights_k(const float* __restrict__ kpart, const float* __restrict__ qscale,
               float* __restrict__ weights) {
  int i = blockIdx.x * 256 + threadIdx.x;  // t*64 + h
  int t = i >> 6, h = i & 63;
  float s = 0.0f;
#pragma unroll
  for (int p = 0; p < KSPLIT; p++)
    s = __fadd_rn(s, kpart[(size_t)p * (NT * 192) + t * 192 + 128 + h]);
  float w = __fmul_rn(s, 0.125f);
  w = __fmul_rn(w, qscale[i]);
  w = __fmul_rn(w, 0.08838834764831843f);
  weights[i] = w;
}

// ------------------------------------------------------------------- scores
// Block = (4-t tile, 128-s chunk); grid 1152. Q+K staged in LDS via
// global_load_lds with a 16B-granule XOR swizzle (G ^= (row>>1)&7) so that
// ds_read_b64 fragment reads are <=2-way bank-aliased (free). Wave w covers
// s in [w*32, w*32+32) for all 64 heads; h-sum completed in-wave -> scores
// final (kscale factored out, applied in topk; exact for pow2 scales).
__global__ __launch_bounds__(256)
void scores_k(const uint8_t* __restrict__ qfp8, const uint8_t* __restrict__ kfp8,
              const float* __restrict__ weights, float* __restrict__ scores) {
  __shared__ uint8_t q_lds[TTILE * 64 * 128];  // 32KB
  __shared__ uint8_t k_lds[128 * 128];         // 16KB
  __shared__ float w_lds[TTILE * 64];          // 1KB

  int b = blockIdx.x;
  int g = 0;  // t-tile group: tiles [32g,32g+32) have g+1 s-chunks
  while (g < 7 && b >= 16 * (g + 1) * (g + 2)) g++;
  int r = b - 16 * g * (g + 1);
  int a = 32 * g + r / (g + 1);
  int chunk = r % (g + 1);
  int t0 = a * TTILE;
  int s0 = chunk * 128;

  int tid = threadIdx.x;
  int wave = tid >> 6, lane = tid & 63;
  int lg = lane >> 4, ln = lane & 15;

  // ---- stage Q (256 rows x 128B) with inverse-swizzled source, linear dest
  const uint8_t* qbase = qfp8 + (size_t)t0 * 64 * 128;
#pragma unroll
  for (int it = 0; it < 8; it++) {
    int o = it * 256 + wave * 64 + lane;  // 16B-granule index
    int row = o >> 3, G = o & 7;
    int src = row * 128 + ((G ^ ((row >> 1) & 7)) << 4);
    gload_lds16(qbase + src, q_lds + (it * 256 + wave * 64) * 16);
  }
  // ---- stage K (128 rows x 128B)
  const uint8_t* kbase = kfp8 + (size_t)s0 * 128;
#pragma unroll
  for (int it = 0; it < 4; it++) {
    int o = it * 256 + wave * 64 + lane;
    int row = o >> 3, G = o & 7;
    int src = row * 128 + ((G ^ ((row >> 1) & 7)) << 4);
    gload_lds16(kbase + src, k_lds + (it * 256 + wave * 64) * 16);
  }
  w_lds[tid] = weights[t0 * NH + tid];
  __syncthreads();

  // ---- K fragments: loaded once, reused for all 4 t and 4 h-tiles
  long bfr[2][4];
#pragma unroll
  for (int sj = 0; sj < 2; sj++) {
    int srow = wave * 32 + sj * 16 + ln;
    int base = srow * 128;
    int xr = ((srow >> 1) & 7) << 4;
#pragma unroll
    for (int ks = 0; ks < 4; ks++)
      bfr[sj][ks] = *(const long*)(k_lds + base + ((ks * 32 + lg * 8) ^ xr));
  }

  float p[TTILE][2];
#pragma unroll
  for (int tt = 0; tt < TTILE; tt++) p[tt][0] = p[tt][1] = 0.0f;

#pragma unroll
  for (int ht = 0; ht < 4; ht++) {  // head tiles of 16
    long afr[TTILE][4];
#pragma unroll
    for (int tt = 0; tt < TTILE; tt++) {
      int qrow = tt * 64 + ht * 16 + ln;
      int base = qrow * 128;
      int xr = ((qrow >> 1) & 7) << 4;
#pragma unroll
      for (int ks = 0; ks < 4; ks++)
        afr[tt][ks] = *(const long*)(q_lds + base + ((ks * 32 + lg * 8) ^ xr));
    }
#pragma unroll
    for (int tt = 0; tt < TTILE; tt++) {
      float wj[4];
#pragma unroll
      for (int j = 0; j < 4; j++) wj[j] = w_lds[tt * 64 + ht * 16 + lg * 4 + j];
#pragma unroll
      for (int sj = 0; sj < 2; sj++) {
        f32x4 acc = {0.f, 0.f, 0.f, 0.f};
#pragma unroll
        for (int ks = 0; ks < 4; ks++)
          acc = __builtin_amdgcn_mfma_f32_16x16x32_fp8_fp8(afr[tt][ks], bfr[sj][ks],
                                                           acc, 0, 0, 0);
#pragma unroll
        for (int j = 0; j < 4; j++)
          p[tt][sj] = fmaf(wj[j], fmaxf(acc[j], 0.0f), p[tt][sj]);
      }
    }
  }

#pragma unroll
  for (int tt = 0; tt < TTILE; tt++)
#pragma unroll
    for (int sj = 0; sj < 2; sj++) {
      float v = p[tt][sj];
      v += __shfl_xor(v, 16, 64);
      v += __shfl_xor(v, 32, 64);
      if (lg == 0)
        scores[(size_t)(t0 + tt) * NT + s0 + wave * 32 + sj * 16 + ln] = v;
    }
}

// -------------------------------------------------------------------- top-k
__global__ __launch_bounds__(256)
void topk_k(const float* __restrict__ scores, const float* __restrict__ kscale,
            float* __restrict__ outv, float* __restrict__ outi) {
  __shared__ unsigned long long key[1024];
  int t = blockIdx.x, tid = threadIdx.x;
#pragma unroll
  for (int p = 0; p < 4; p++) {
    int s = tid + p * 256;
    float v;
    if (s <= t) {
      v = __fmul_rn(scores[(size_t)t * NT + s], kscale[s]);  // exact pow2 factor
    } else {
      v = -1e30f;
    }
    unsigned u = __float_as_uint(v);
    unsigned ou = (u & 0x80000000u) ? ~u : (u | 0x80000000u);
    key[s] = ((unsigned long long)ou << 32) | (unsigned)(~(unsigned)s);
  }
  for (int k = 2; k <= 1024; k <<= 1) {
    for (int j = k >> 1; j > 0; j >>= 1) {
      __syncthreads();
#pragma unroll
      for (int p = 0; p < 2; p++) {
        int i = tid + p * 256;
        int l = ((i & ~(j - 1)) << 1) | (i & (j - 1));
        int m = l + j;
        bool desc = ((l & k) == 0);
        unsigned long long a = key[l], b = key[m];
        if (desc ? (a < b) : (a > b)) {
          key[l] = b;
          key[m] = a;
        }
      }
    }
  }
  __syncthreads();
#pragma unroll
  for (int p = 0; p < 2; p++) {
    int r = tid + p * 256;
    unsigned long long kk = key[r];
    unsigned ou = (unsigned)(kk >> 32);
    unsigned u = (ou & 0x80000000u) ? (ou ^ 0x80000000u) : ~ou;
    unsigned idx = (~(unsigned)(kk & 0xffffffffu)) & 1023u;
    outv[(size_t)t * NTOPK + r] = __uint_as_float(u);
    outi[(size_t)t * NTOPK + r] = (float)idx;
  }
}

// ------------------------------------------------------------------- launch
extern "C" void kernel_launch(void* const* d_in, const int* in_sizes, int n_in,
                              void* d_out, int out_size, void* d_ws, size_t ws_size,
                              hipStream_t stream) {
  const float* hidden = (const float*)d_in[0];
  const float* q_lora = (const float*)d_in[1];
  const int* positions = (const int*)d_in[2];
  const float* wq_b = (const float*)d_in[3];
  const float* wk = (const float*)d_in[4];
  const float* w_proj = (const float*)d_in[5];
  const float* ln_g = (const float*)d_in[6];
  const float* ln_b = (const float*)d_in[7];
  float* out = (float*)d_out;

  // ---- workspace layout (phase-aliased union region first)
  char* u0 = (char*)d_ws;
  // phase A (hidden-proj): hidden_bf [1024][7168], wkp_t [192][7168]
  ushort* hiddenb = (ushort*)u0;                       // 14,680,064 B
  ushort* wkpt = (ushort*)(u0 + 14680064);             //  2,752,512 B
  // phase B (q): wqb_t [8192][1536], qlora_bf [1024][1536]
  ushort* wqbt = (ushort*)u0;                          // 25,165,824 B
  ushort* qlorab = (ushort*)(u0 + 25165824);           //  3,145,728 B
  // phase C (scores): scores [1024][1024] f32
  float* scores = (float*)u0;                          //  4,194,304 B
  char* p = u0 + 28311552;
  float* kpart = (float*)p;    p += 12582912;          // [16][1024][192] f32
  float* cost = (float*)p;     p += 131072;
  float* sint = (float*)p;     p += 131072;
  float* kscale = (float*)p;   p += 4096;
  float* qscale = (float*)p;   p += 262144;
  float* weights = (float*)p;  p += 262144;
  uint8_t* kfp8 = (uint8_t*)p; p += 131072;
  uint8_t* qfp8 = (uint8_t*)p; p += 8388608;

  rope_table_k<<<NT, 64, 0, stream>>>(positions, cost, sint);

  // phase A: k + weights projections (combined B = [wk | w_proj], N=192)
  cast_bf16_k<<<NT * NHID / 8 / 256, 256, 0, stream>>>(hidden, hiddenb, NT * NHID / 8);
  tcast_k<<<dim3(2, 112), 256, 0, stream>>>(wk, wkpt, NHID, ND);
  tcast_k<<<dim3(1, 112), 256, 0, stream>>>(w_proj, wkpt + 128 * NHID, NHID, NH);
  gemm_bf16_k<64, false><<<dim3(3, 8, KSPLIT), 256, 0, stream>>>(
      hiddenb, wkpt, kpart, NT, 192, NHID, NHID / KSPLIT,
      nullptr, nullptr, nullptr, nullptr);

  // phase B: q projection + fused rope/FWHT/fp8-quant epilogue
  cast_bf16_k<<<NT * NR / 8 / 256, 256, 0, stream>>>(q_lora, qlorab, NT * NR / 8);
  tcast_k<<<dim3(128, 24), 256, 0, stream>>>(wq_b, wqbt, NR, NH * ND);
  gemm_bf16_k<128, true><<<dim3(64, 8, 1), 256, 0, stream>>>(
      qlorab, wqbt, nullptr, NT, NH * ND, NR, NR,
      cost, sint, qfp8, qscale);

  k_finalize_k<<<NT / 4, 256, 0, stream>>>(kpart, ln_g, ln_b, cost, sint, kfp8, kscale);
  weights_k<<<NT * NH / 256, 256, 0, stream>>>(kpart, qscale, weights);

  // phase C: scores (overwrites phase-B cast buffers) + top-k
  scores_k<<<1152, 256, 0, stream>>>(qfp8, kfp8, weights, scores);
  topk_k<<<NT, 256, 0, stream>>>(scores, kscale, out, out + (size_t)NT * NTOPK);
}